// Round 2
// 511.521 us; speedup vs baseline: 1.1014x; 1.1014x over previous
//
#include <hip/hip_runtime.h>
#include <hip/hip_bf16.h>

#define NODES 50000
#define NEDGE 800000
#define ETOT  850000   /* NEDGE + NODES self loops */

typedef __hip_bfloat16 bf16;
typedef __attribute__((ext_vector_type(8))) short bf16x8;
typedef __attribute__((ext_vector_type(4))) float f32x4;

__device__ __forceinline__ bf16 f2bf(float v) { return __float2bfloat16(v); }
__device__ __forceinline__ float bflo(unsigned int v) { return __uint_as_float(v << 16); }
__device__ __forceinline__ float bfhi(unsigned int v) { return __uint_as_float(v & 0xffff0000u); }

__device__ __forceinline__ unsigned int pack2(float a, float b) {
    bf16 x = f2bf(a), y = f2bf(b);
    unsigned short xs = *reinterpret_cast<unsigned short*>(&x);
    unsigned short ys = *reinterpret_cast<unsigned short*>(&y);
    return ((unsigned int)ys << 16) | (unsigned int)xs;
}

__device__ __forceinline__ unsigned short bfbits(float v) {
    bf16 x = f2bf(v);
    return *reinterpret_cast<unsigned short*>(&x);
}

// split 8 fp32 -> hi/lo bf16x8 (Dekker split: lo = v - float(hi), exact)
__device__ __forceinline__ void split8(const float* v, bf16x8& hi, bf16x8& lo) {
    #pragma unroll
    for (int e = 0; e < 8; ++e) {
        unsigned short hb = bfbits(v[e]);
        float hv = __uint_as_float((unsigned int)hb << 16);
        unsigned short lb = bfbits(v[e] - hv);
        ((short*)&hi)[e] = (short)hb;
        ((short*)&lo)[e] = (short)lb;
    }
}

// ---------------------------------------------------------------------------
// k_prep: histogram of dst (incl. self loops) + sum of edge_attr (for mean)
// [byte-identical to passing R10]
// ---------------------------------------------------------------------------
__global__ __launch_bounds__(256) void k_prep(const float* edge_attr, const int* ei,
                                              float* sum_ea, int* count) {
    int tid = blockIdx.x * blockDim.x + threadIdx.x;
    int stride = gridDim.x * blockDim.x;
    float local = 0.f;
    for (int e = tid; e < ETOT; e += stride) {
        int dst = (e < NEDGE) ? ei[NEDGE + e] : (e - NEDGE);
        atomicAdd(&count[dst], 1);
        if (e < NEDGE) local += edge_attr[e];
    }
    #pragma unroll
    for (int s = 1; s < 64; s <<= 1) local += __shfl_xor(local, s, 64);
    if ((threadIdx.x & 63) == 0) atomicAdd(sum_ea, local);
}

// ---------------------------------------------------------------------------
// k_xform: xl = x@W_l + b_l ; xr = x@W_r + b_r  [byte-identical to passing R10]
// ---------------------------------------------------------------------------
__global__ __launch_bounds__(256) void k_xform(const float* x,
                                               const float* W_l, const float* b_l,
                                               const float* W_r, const float* b_r,
                                               bf16* xl, bf16* xr) {
    __shared__ __align__(16) float s_x[32][132];
    const int tid = threadIdx.x;
    const int n0 = blockIdx.x * 32;
    for (int it = 0; it < 4; ++it) {
        int idx4 = (it * 256 + tid) * 4;
        int n = idx4 >> 7, j = idx4 & 127;
        int node = n0 + n;
        float4 v = make_float4(0.f, 0.f, 0.f, 0.f);
        if (node < NODES) v = *(const float4*)(x + node * 128 + j);
        *(float4*)&s_x[n][j] = v;
    }
    __syncthreads();
    const int mat = tid >> 7;
    const int ng  = (tid >> 5) & 3;
    const int cg  = tid & 31;
    const float* W  = mat ? W_r : W_l;
    const float* bb = mat ? b_r : b_l;
    bf16* dst = mat ? xr : xl;
    const int c0 = cg * 4, nb = ng * 8;
    float acc[4][8];
    #pragma unroll
    for (int c = 0; c < 4; ++c)
        #pragma unroll
        for (int n = 0; n < 8; ++n) acc[c][n] = 0.f;
    for (int k = 0; k < 128; ++k) {
        float4 w = *(const float4*)(W + k * 128 + c0);
        #pragma unroll
        for (int n = 0; n < 8; ++n) {
            float xv = s_x[nb + n][k];
            acc[0][n] += xv * w.x;
            acc[1][n] += xv * w.y;
            acc[2][n] += xv * w.z;
            acc[3][n] += xv * w.w;
        }
    }
    float4 bv = *(const float4*)(bb + c0);
    for (int n = 0; n < 8; ++n) {
        int node = n0 + nb + n;
        if (node < NODES) {
            uint2 u;
            u.x = pack2(acc[0][n] + bv.x, acc[1][n] + bv.y);
            u.y = pack2(acc[2][n] + bv.z, acc[3][n] + bv.w);
            *(uint2*)(dst + node * 128 + c0) = u;
        }
    }
}

// ---------------------------------------------------------------------------
// k_scan: exclusive prefix sum of count -> off, init cursor = off.
// [byte-identical to passing R10]
// ---------------------------------------------------------------------------
__global__ __launch_bounds__(1024) void k_scan(const int* count, int* off, int* cursor) {
    __shared__ int s[1024];
    const int t = threadIdx.x;
    const int CHUNK = (NODES + 1023) / 1024;  // 49
    int lo = t * CHUNK;
    int hi = lo + CHUNK; if (hi > NODES) hi = NODES; if (lo > NODES) lo = NODES;
    int sum = 0;
    for (int i = lo; i < hi; ++i) sum += count[i];
    s[t] = sum;
    __syncthreads();
    for (int st = 1; st < 1024; st <<= 1) {
        int v = 0;
        if (t >= st) v = s[t - st];
        __syncthreads();
        if (t >= st) s[t] += v;
        __syncthreads();
    }
    int run = (t == 0) ? 0 : s[t - 1];
    for (int i = lo; i < hi; ++i) {
        off[i] = run; cursor[i] = run; run += count[i];
    }
    if (t == 1023) off[NODES] = s[1023];
}

// ---------------------------------------------------------------------------
// k_wconv: transpose FFN weights to [col][k] and split into hi/lo bf16 pairs
// (hi = bf16(w), lo = bf16(w - hi)). Runs AFTER k_place so both the `count`
// and `cursor` workspace regions are dead and can hold the 4 arrays.
// ---------------------------------------------------------------------------
__global__ __launch_bounds__(256) void k_wconv(const float* W1, const float* W2,
                                               bf16* w1h, bf16* w1l,
                                               bf16* w2h, bf16* w2l) {
    int tid = blockIdx.x * blockDim.x + threadIdx.x;   // 65536 threads
    if (tid < 32768) {
        int c = tid >> 7, k = tid & 127;               // w1t[c][k]
        float v = W1[k * 256 + c];
        unsigned short hb = bfbits(v);
        float hv = __uint_as_float((unsigned int)hb << 16);
        w1h[tid] = f2bf(v);
        w1l[tid] = f2bf(v - hv);
    } else {
        int t = tid - 32768;
        int c = t >> 8, k = t & 255;                   // w2t[c][k]
        float v = W2[k * 128 + c];
        unsigned short hb = bfbits(v);
        float hv = __uint_as_float((unsigned int)hb << 16);
        w2h[t] = f2bf(v);
        w2l[t] = f2bf(v - hv);
    }
}

// ---------------------------------------------------------------------------
// k_place: perm[pos] = (ea_bf16_bits << 16) | src, grouped by dst.
// [byte-identical to passing R10]
// ---------------------------------------------------------------------------
__global__ __launch_bounds__(256) void k_place(const int* ei, const float* edge_attr,
                                               const float* sum_ea,
                                               int* cursor, unsigned int* perm) {
    const float meanv = sum_ea[0] * (1.f / (float)NEDGE);
    int tid = blockIdx.x * blockDim.x + threadIdx.x;
    int stride = gridDim.x * blockDim.x;
    for (int e = tid; e < ETOT; e += stride) {
        int src, dst; float eav;
        if (e < NEDGE) { src = ei[e]; dst = ei[NEDGE + e]; eav = edge_attr[e]; }
        else           { src = e - NEDGE; dst = src; eav = meanv; }
        int pos = atomicAdd(&cursor[dst], 1);
        perm[pos] = ((unsigned int)bfbits(eav) << 16) | (unsigned int)src;
    }
}

// ---------------------------------------------------------------------------
// k_agg: [byte-identical to passing R10]
// ---------------------------------------------------------------------------
__global__ __launch_bounds__(256) void k_agg(const unsigned int* xl32,
                                             const unsigned int* xr32,
                                             const unsigned int* perm, const int* off,
                                             const float* W_e, const float* att,
                                             float* outp) {
    const int lane = threadIdx.x & 63;
    const int wave0 = blockIdx.x * 4 + (threadIdx.x >> 6);
    const int nwaves = gridDim.x * 4;
    const int c = 2 * lane;
    const float we1 = W_e[c], we2 = W_e[c + 1];
    const float a1 = att[c], a2 = att[c + 1];
    for (int n = wave0; n < NODES; n += nwaves) {
        unsigned int xru = xr32[n * 64 + lane];
        float xr1 = bflo(xru), xr2 = bfhi(xru);
        int s0 = off[n], s1 = off[n + 1];
        float m = -1e30f, l = 0.f, acc1 = 0.f, acc2 = 0.f;
        int j = s0;
        for (; j + 4 <= s1; j += 4) {
            unsigned int u0 = perm[j];
            unsigned int u1 = perm[j + 1];
            unsigned int u2 = perm[j + 2];
            unsigned int u3 = perm[j + 3];
            unsigned int g0 = xl32[(u0 & 0xffffu) * 64 + lane];
            unsigned int g1 = xl32[(u1 & 0xffffu) * 64 + lane];
            unsigned int g2 = xl32[(u2 & 0xffffu) * 64 + lane];
            unsigned int g3 = xl32[(u3 & 0xffffu) * 64 + lane];
            float e0 = bfhi(u0), e1 = bfhi(u1), e2 = bfhi(u2), e3 = bfhi(u3);
            float x01 = bflo(g0), x02 = bfhi(g0);
            float x11 = bflo(g1), x12 = bfhi(g1);
            float x21 = bflo(g2), x22 = bfhi(g2);
            float x31 = bflo(g3), x32 = bfhi(g3);
            float p0, p1, p2, p3;
            {
                float v1 = x01 + xr1 + e0 * we1, v2 = x02 + xr2 + e0 * we2;
                v1 = (v1 > 0.f) ? v1 : 0.2f * v1;
                v2 = (v2 > 0.f) ? v2 : 0.2f * v2;
                p0 = v1 * a1 + v2 * a2;
            }
            {
                float v1 = x11 + xr1 + e1 * we1, v2 = x12 + xr2 + e1 * we2;
                v1 = (v1 > 0.f) ? v1 : 0.2f * v1;
                v2 = (v2 > 0.f) ? v2 : 0.2f * v2;
                p1 = v1 * a1 + v2 * a2;
            }
            {
                float v1 = x21 + xr1 + e2 * we1, v2 = x22 + xr2 + e2 * we2;
                v1 = (v1 > 0.f) ? v1 : 0.2f * v1;
                v2 = (v2 > 0.f) ? v2 : 0.2f * v2;
                p2 = v1 * a1 + v2 * a2;
            }
            {
                float v1 = x31 + xr1 + e3 * we1, v2 = x32 + xr2 + e3 * we2;
                v1 = (v1 > 0.f) ? v1 : 0.2f * v1;
                v2 = (v2 > 0.f) ? v2 : 0.2f * v2;
                p3 = v1 * a1 + v2 * a2;
            }
            p0 += __shfl_xor(p0, 1, 64); p1 += __shfl_xor(p1, 1, 64);
            p2 += __shfl_xor(p2, 1, 64); p3 += __shfl_xor(p3, 1, 64);
            p0 += __shfl_xor(p0, 2, 64); p1 += __shfl_xor(p1, 2, 64);
            p2 += __shfl_xor(p2, 2, 64); p3 += __shfl_xor(p3, 2, 64);
            p0 += __shfl_xor(p0, 4, 64); p1 += __shfl_xor(p1, 4, 64);
            p2 += __shfl_xor(p2, 4, 64); p3 += __shfl_xor(p3, 4, 64);
            p0 += __shfl_xor(p0, 8, 64); p1 += __shfl_xor(p1, 8, 64);
            p2 += __shfl_xor(p2, 8, 64); p3 += __shfl_xor(p3, 8, 64);
            float nm = fmaxf(fmaxf(m, fmaxf(p0, p1)), fmaxf(p2, p3));
            float sc = __expf(m - nm);
            float E0 = __expf(p0 - nm);
            float E1 = __expf(p1 - nm);
            float E2 = __expf(p2 - nm);
            float E3 = __expf(p3 - nm);
            l = l * sc + E0 + E1 + E2 + E3;
            acc1 = acc1 * sc + E0 * x01 + E1 * x11 + E2 * x21 + E3 * x31;
            acc2 = acc2 * sc + E0 * x02 + E1 * x12 + E2 * x22 + E3 * x32;
            m = nm;
        }
        for (; j < s1; ++j) {
            unsigned int u0 = perm[j];
            unsigned int g0 = xl32[(u0 & 0xffffu) * 64 + lane];
            float e0 = bfhi(u0);
            float x01 = bflo(g0), x02 = bfhi(g0);
            float v1 = x01 + xr1 + e0 * we1, v2 = x02 + xr2 + e0 * we2;
            v1 = (v1 > 0.f) ? v1 : 0.2f * v1;
            v2 = (v2 > 0.f) ? v2 : 0.2f * v2;
            float p = v1 * a1 + v2 * a2;
            p += __shfl_xor(p, 1, 64);
            p += __shfl_xor(p, 2, 64);
            p += __shfl_xor(p, 4, 64);
            p += __shfl_xor(p, 8, 64);
            float nm = fmaxf(m, p);
            float sc = __expf(m - nm);
            float ee = __expf(p - nm);
            l = l * sc + ee;
            acc1 = acc1 * sc + ee * x01;
            acc2 = acc2 * sc + ee * x02;
            m = nm;
        }
        float inv = 1.f / fmaxf(l, 1e-30f);
        *(float2*)(outp + n * 128 + c) = make_float2(acc1 * inv, acc2 * inv);
    }
}

// ---------------------------------------------------------------------------
// k_epi (split-precision MFMA): FFN1/FFN2 via mfma_f32_16x16x32_bf16 with
// hi/lo bf16 operand splits: A*B ~= Ah*Bh + Ah*Bl + Al*Bh (near-fp32).
// A-fragments split in-register from fp32 LDS (s_y stride 132, s_t stride
// 260 -> both 4-word bank stagger, worst 2-way alias = free).
// A frag: row=lane&15, k=(lane>>4)*8+e.  D: col=lane&15, row=(lane>>4)*4+r
// [m89/m97 ref-checked; structure HW-validated last round, numerics only].
// ---------------------------------------------------------------------------
__global__ __launch_bounds__(256) void k_epi(const float* out_agg, const float* x,
                                             const float* bias_out,
                                             const float* W_gate, const float* b_gate,
                                             const bf16* w1h, const bf16* w1l,
                                             const float* b_ffn1,
                                             const bf16* w2h, const bf16* w2l,
                                             const float* b_ffn2,
                                             const float* gamma, const float* beta,
                                             float* out) {
    __shared__ __align__(16) float s_y[32][132];   // h, then y (fp32; residual+LN+FFN1 A)
    __shared__ __align__(16) float s_t[32][260];   // relu(ffn1) fp32 (FFN2 A)
    __shared__ float s_g[32];
    __shared__ float s_mu[32], s_rs[32];
    const int tid = threadIdx.x;
    const int n0 = blockIdx.x * 32;
    int nn = NODES - n0; if (nn > 32) nn = 32;

    // phase 1: h = elu(out_agg + bias_out) -> s_y
    for (int it = 0; it < 4; ++it) {
        int idx4 = (it * 256 + tid) * 4;
        int n = idx4 >> 7, j = idx4 & 127;
        float4 w = make_float4(0.f, 0.f, 0.f, 0.f);
        if (n < nn) {
            float4 v  = *(const float4*)(out_agg + (n0 + n) * 128 + j);
            float4 bv = *(const float4*)(bias_out + j);
            float t0 = v.x + bv.x, t1 = v.y + bv.y;
            float t2 = v.z + bv.z, t3 = v.w + bv.w;
            w.x = (t0 > 0.f) ? t0 : (__expf(t0) - 1.f);
            w.y = (t1 > 0.f) ? t1 : (__expf(t1) - 1.f);
            w.z = (t2 > 0.f) ? t2 : (__expf(t2) - 1.f);
            w.w = (t3 > 0.f) ? t3 : (__expf(t3) - 1.f);
        }
        *(float4*)&s_y[n][j] = w;
    }
    __syncthreads();
    // gate: 8 threads per node, shfl-reduce within 8-lane groups
    {
        int n = tid >> 3, kb = (tid & 7) * 16;
        float g = 0.f;
        #pragma unroll
        for (int k = 0; k < 16; k += 4) {
            float4 w = *(const float4*)(W_gate + kb + k);
            float4 h = *(const float4*)&s_y[n][kb + k];
            g += h.x * w.x + h.y * w.y + h.z * w.z + h.w * w.w;
        }
        g += __shfl_xor(g, 1, 64);
        g += __shfl_xor(g, 2, 64);
        g += __shfl_xor(g, 4, 64);
        if ((tid & 7) == 0) s_g[n] = 1.f / (1.f + __expf(-(g + b_gate[0])));
    }
    __syncthreads();
    // y = g*h + (1-g)*x -> s_y (fp32)
    for (int it = 0; it < 4; ++it) {
        int idx4 = (it * 256 + tid) * 4;
        int n = idx4 >> 7, j = idx4 & 127;
        if (n < nn) {
            float g = s_g[n];
            float4 xv = *(const float4*)(x + (n0 + n) * 128 + j);
            float4 h = *(float4*)&s_y[n][j];
            h.x = g * h.x + (1.f - g) * xv.x;
            h.y = g * h.y + (1.f - g) * xv.y;
            h.z = g * h.z + (1.f - g) * xv.z;
            h.w = g * h.w + (1.f - g) * xv.w;
            *(float4*)&s_y[n][j] = h;
        }
    }
    __syncthreads();

    const int wv   = tid >> 6;          // wave 0..3
    const int ln   = tid & 63;
    const int lrow = ln & 15;           // A row / B,D col within tile
    const int lk8  = (ln >> 4) << 3;    // k chunk base: 0,8,16,24

    // FFN1: t = relu(y @ W1 + b1). M=32 (2 tiles), per-wave N=64 (4 tiles), K=128.
    f32x4 acc1[2][4];
    #pragma unroll
    for (int mt = 0; mt < 2; ++mt)
        #pragma unroll
        for (int i = 0; i < 4; ++i)
            acc1[mt][i] = (f32x4){0.f, 0.f, 0.f, 0.f};
    #pragma unroll
    for (int kk = 0; kk < 4; ++kk) {
        int k0 = kk * 32 + lk8;
        float a0f[8], a1f[8];
        *(float4*)&a0f[0] = *(const float4*)&s_y[lrow][k0];
        *(float4*)&a0f[4] = *(const float4*)&s_y[lrow][k0 + 4];
        *(float4*)&a1f[0] = *(const float4*)&s_y[16 + lrow][k0];
        *(float4*)&a1f[4] = *(const float4*)&s_y[16 + lrow][k0 + 4];
        bf16x8 a0h, a0l, a1h, a1l;
        split8(a0f, a0h, a0l);
        split8(a1f, a1h, a1l);
        #pragma unroll
        for (int i = 0; i < 4; ++i) {
            int col = (wv << 6) + (i << 4) + lrow;
            bf16x8 bh = *(const bf16x8*)(w1h + col * 128 + k0);
            bf16x8 bl = *(const bf16x8*)(w1l + col * 128 + k0);
            acc1[0][i] = __builtin_amdgcn_mfma_f32_16x16x32_bf16(a0l, bh, acc1[0][i], 0, 0, 0);
            acc1[0][i] = __builtin_amdgcn_mfma_f32_16x16x32_bf16(a0h, bl, acc1[0][i], 0, 0, 0);
            acc1[0][i] = __builtin_amdgcn_mfma_f32_16x16x32_bf16(a0h, bh, acc1[0][i], 0, 0, 0);
            acc1[1][i] = __builtin_amdgcn_mfma_f32_16x16x32_bf16(a1l, bh, acc1[1][i], 0, 0, 0);
            acc1[1][i] = __builtin_amdgcn_mfma_f32_16x16x32_bf16(a1h, bl, acc1[1][i], 0, 0, 0);
            acc1[1][i] = __builtin_amdgcn_mfma_f32_16x16x32_bf16(a1h, bh, acc1[1][i], 0, 0, 0);
        }
    }
    // epilogue: +b1, relu -> s_t (fp32; lanes 0-15 write consecutive cols)
    #pragma unroll
    for (int mt = 0; mt < 2; ++mt) {
        #pragma unroll
        for (int i = 0; i < 4; ++i) {
            int col = (wv << 6) + (i << 4) + lrow;
            float bv = b_ffn1[col];
            #pragma unroll
            for (int r = 0; r < 4; ++r) {
                int row = (mt << 4) + ((ln >> 4) << 2) + r;
                s_t[row][col] = fmaxf(acc1[mt][i][r] + bv, 0.f);
            }
        }
    }
    __syncthreads();

    // FFN2: ffn = t @ W2 + b2. M=32 (2 tiles), per-wave N=32 (2 tiles), K=256.
    f32x4 acc2[2][2];
    #pragma unroll
    for (int mt = 0; mt < 2; ++mt)
        #pragma unroll
        for (int c = 0; c < 2; ++c)
            acc2[mt][c] = (f32x4){0.f, 0.f, 0.f, 0.f};
    #pragma unroll
    for (int kk = 0; kk < 8; ++kk) {
        int k0 = kk * 32 + lk8;
        float a0f[8], a1f[8];
        *(float4*)&a0f[0] = *(const float4*)&s_t[lrow][k0];
        *(float4*)&a0f[4] = *(const float4*)&s_t[lrow][k0 + 4];
        *(float4*)&a1f[0] = *(const float4*)&s_t[16 + lrow][k0];
        *(float4*)&a1f[4] = *(const float4*)&s_t[16 + lrow][k0 + 4];
        bf16x8 a0h, a0l, a1h, a1l;
        split8(a0f, a0h, a0l);
        split8(a1f, a1h, a1l);
        #pragma unroll
        for (int c = 0; c < 2; ++c) {
            int col = (wv << 5) + (c << 4) + lrow;
            bf16x8 bh = *(const bf16x8*)(w2h + col * 256 + k0);
            bf16x8 bl = *(const bf16x8*)(w2l + col * 256 + k0);
            acc2[0][c] = __builtin_amdgcn_mfma_f32_16x16x32_bf16(a0l, bh, acc2[0][c], 0, 0, 0);
            acc2[0][c] = __builtin_amdgcn_mfma_f32_16x16x32_bf16(a0h, bl, acc2[0][c], 0, 0, 0);
            acc2[0][c] = __builtin_amdgcn_mfma_f32_16x16x32_bf16(a0h, bh, acc2[0][c], 0, 0, 0);
            acc2[1][c] = __builtin_amdgcn_mfma_f32_16x16x32_bf16(a1l, bh, acc2[1][c], 0, 0, 0);
            acc2[1][c] = __builtin_amdgcn_mfma_f32_16x16x32_bf16(a1h, bl, acc2[1][c], 0, 0, 0);
            acc2[1][c] = __builtin_amdgcn_mfma_f32_16x16x32_bf16(a1h, bh, acc2[1][c], 0, 0, 0);
        }
    }
    // epilogue: y += ffn + b2  (disjoint (row,col) per lane across block)
    #pragma unroll
    for (int mt = 0; mt < 2; ++mt) {
        #pragma unroll
        for (int c = 0; c < 2; ++c) {
            int col = (wv << 5) + (c << 4) + lrow;
            float bv = b_ffn2[col];
            #pragma unroll
            for (int r = 0; r < 4; ++r) {
                int row = (mt << 4) + ((ln >> 4) << 2) + r;
                s_y[row][col] += acc2[mt][c][r] + bv;
            }
        }
    }
    __syncthreads();
    // LayerNorm stats: 8 threads per node
    {
        int n = tid >> 3, kb = (tid & 7) * 16;
        float s = 0.f, ss = 0.f;
        #pragma unroll
        for (int k = 0; k < 16; k += 4) {
            float4 v = *(const float4*)&s_y[n][kb + k];
            s  += v.x + v.y + v.z + v.w;
            ss += v.x * v.x + v.y * v.y + v.z * v.z + v.w * v.w;
        }
        s  += __shfl_xor(s, 1, 64);  ss += __shfl_xor(ss, 1, 64);
        s  += __shfl_xor(s, 2, 64);  ss += __shfl_xor(ss, 2, 64);
        s  += __shfl_xor(s, 4, 64);  ss += __shfl_xor(ss, 4, 64);
        if ((tid & 7) == 0) {
            float mu = s * (1.f / 128.f);
            float var = ss * (1.f / 128.f) - mu * mu;
            s_mu[n] = mu;
            s_rs[n] = rsqrtf(fmaxf(var, 0.f) + 1e-5f);
        }
    }
    __syncthreads();
    // normalize + store (fp32)
    for (int it = 0; it < 4; ++it) {
        int idx4 = (it * 256 + tid) * 4;
        int n = idx4 >> 7, j = idx4 & 127;
        if (n < nn) {
            float mu = s_mu[n], rs = s_rs[n];
            float4 gv = *(const float4*)(gamma + j);
            float4 bv = *(const float4*)(beta + j);
            float4 v = *(const float4*)&s_y[n][j];
            float4 o;
            o.x = (v.x - mu) * rs * gv.x + bv.x;
            o.y = (v.y - mu) * rs * gv.y + bv.y;
            o.z = (v.z - mu) * rs * gv.z + bv.z;
            o.w = (v.w - mu) * rs * gv.w + bv.w;
            *(float4*)(out + (n0 + n) * 128 + j) = o;
        }
    }
}

// ---------------------------------------------------------------------------
extern "C" void kernel_launch(void* const* d_in, const int* in_sizes, int n_in,
                              void* d_out, int out_size, void* d_ws, size_t ws_size,
                              hipStream_t stream) {
    const float* x         = (const float*)d_in[0];
    const float* edge_attr = (const float*)d_in[1];
    const int* edge_index  = (const int*)d_in[17];
    float* out = (float*)d_out;

    char* base = (char*)d_ws;
    // workspace layout: EXACTLY the hardware-proven layout (29,600,064 B).
    float* sum_ea  = (float*)(base + 16);                     // 16
    int*   count   = (int*)  (base + 32);                     // 200000
    int*   off     = (int*)  (base + 200032);                 // 200004 (+pad)
    int*   cursor  = (int*)  (base + 400064);                 // 200000
    unsigned int* perm = (unsigned int*)(base + 600064);      // 3400000
    bf16*  xl      = (bf16*) (base + 4000064);                // 12800000
    bf16*  xr      = (bf16*) (base + 16800064);               // 12800000
    // split bf16 transposed FFN weights:
    //   w1 pair reuses `count` region (dead after k_scan): 131072 B < 200000
    //   w2 pair reuses `cursor` region (dead after k_place): 131072 B < 200000
    bf16*  w1t_hi  = (bf16*) (base + 32);
    bf16*  w1t_lo  = (bf16*) (base + 32 + 65536);
    bf16*  w2t_hi  = (bf16*) (base + 400064);
    bf16*  w2t_lo  = (bf16*) (base + 400064 + 65536);

    hipMemsetAsync(sum_ea, 0, 16, stream);
    hipMemsetAsync(count, 0, NODES * sizeof(int), stream);

    const int NTILES = (NODES + 31) / 32;  // 1563

    k_prep  <<<1024, 256, 0, stream>>>(edge_attr, edge_index, sum_ea, count);
    k_xform <<<NTILES, 256, 0, stream>>>(x, (const float*)d_in[2], (const float*)d_in[3],
                                         (const float*)d_in[4], (const float*)d_in[5],
                                         xl, xr);
    k_scan  <<<1, 1024, 0, stream>>>(count, off, cursor);
    k_place <<<1024, 256, 0, stream>>>(edge_index, edge_attr, sum_ea, cursor, perm);
    k_wconv <<<256, 256, 0, stream>>>((const float*)d_in[11], (const float*)d_in[13],
                                      w1t_hi, w1t_lo, w2t_hi, w2t_lo);
    k_agg   <<<3125, 256, 0, stream>>>((const unsigned int*)xl,
                                       (const unsigned int*)xr,
                                       perm, off,
                                       (const float*)d_in[6], (const float*)d_in[7],
                                       out);
    k_epi   <<<NTILES, 256, 0, stream>>>(out, x, (const float*)d_in[8],
                                         (const float*)d_in[9], (const float*)d_in[10],
                                         w1t_hi, w1t_lo, (const float*)d_in[12],
                                         w2t_hi, w2t_lo, (const float*)d_in[14],
                                         (const float*)d_in[15], (const float*)d_in[16],
                                         out);
}

// Round 4
// 433.956 us; speedup vs baseline: 1.2983x; 1.1787x over previous
//
#include <hip/hip_runtime.h>
#include <hip/hip_bf16.h>

#define NODES 50000
#define NEDGE 800000
#define ETOT  850000   /* NEDGE + NODES self loops */

#define SCHUNK 1024
#define SBLK   ((NODES + SCHUNK - 1) / SCHUNK)   /* 49 */

typedef __hip_bfloat16 bf16;
typedef __attribute__((ext_vector_type(8))) short bf16x8;
typedef __attribute__((ext_vector_type(4))) float f32x4;

__device__ __forceinline__ bf16 f2bf(float v) { return __float2bfloat16(v); }
__device__ __forceinline__ float bflo(unsigned int v) { return __uint_as_float(v << 16); }
__device__ __forceinline__ float bfhi(unsigned int v) { return __uint_as_float(v & 0xffff0000u); }

__device__ __forceinline__ unsigned int pack2(float a, float b) {
    bf16 x = f2bf(a), y = f2bf(b);
    unsigned short xs = *reinterpret_cast<unsigned short*>(&x);
    unsigned short ys = *reinterpret_cast<unsigned short*>(&y);
    return ((unsigned int)ys << 16) | (unsigned int)xs;
}

__device__ __forceinline__ unsigned short bfbits(float v) {
    bf16 x = f2bf(v);
    return *reinterpret_cast<unsigned short*>(&x);
}

// split 8 fp32 -> hi/lo bf16x8 (Dekker split: lo = v - float(hi), exact)
__device__ __forceinline__ void split8(const float* v, bf16x8& hi, bf16x8& lo) {
    #pragma unroll
    for (int e = 0; e < 8; ++e) {
        unsigned short hb = bfbits(v[e]);
        float hv = __uint_as_float((unsigned int)hb << 16);
        unsigned short lb = bfbits(v[e] - hv);
        ((short*)&hi)[e] = (short)hb;
        ((short*)&lo)[e] = (short)lb;
    }
}

// ---------------------------------------------------------------------------
// k_prep: histogram of dst (incl. self loops) + sum of edge_attr (for mean)
// [byte-identical to passing R10]
// ---------------------------------------------------------------------------
__global__ __launch_bounds__(256) void k_prep(const float* edge_attr, const int* ei,
                                              float* sum_ea, int* count) {
    int tid = blockIdx.x * blockDim.x + threadIdx.x;
    int stride = gridDim.x * blockDim.x;
    float local = 0.f;
    for (int e = tid; e < ETOT; e += stride) {
        int dst = (e < NEDGE) ? ei[NEDGE + e] : (e - NEDGE);
        atomicAdd(&count[dst], 1);
        if (e < NEDGE) local += edge_attr[e];
    }
    #pragma unroll
    for (int s = 1; s < 64; s <<= 1) local += __shfl_xor(local, s, 64);
    if ((threadIdx.x & 63) == 0) atomicAdd(sum_ea, local);
}

// ---------------------------------------------------------------------------
// k_xform: xl = x@W_l + b_l ; xr = x@W_r + b_r  [byte-identical to passing R10]
// ---------------------------------------------------------------------------
__global__ __launch_bounds__(256) void k_xform(const float* x,
                                               const float* W_l, const float* b_l,
                                               const float* W_r, const float* b_r,
                                               bf16* xl, bf16* xr) {
    __shared__ __align__(16) float s_x[32][132];
    const int tid = threadIdx.x;
    const int n0 = blockIdx.x * 32;
    for (int it = 0; it < 4; ++it) {
        int idx4 = (it * 256 + tid) * 4;
        int n = idx4 >> 7, j = idx4 & 127;
        int node = n0 + n;
        float4 v = make_float4(0.f, 0.f, 0.f, 0.f);
        if (node < NODES) v = *(const float4*)(x + node * 128 + j);
        *(float4*)&s_x[n][j] = v;
    }
    __syncthreads();
    const int mat = tid >> 7;
    const int ng  = (tid >> 5) & 3;
    const int cg  = tid & 31;
    const float* W  = mat ? W_r : W_l;
    const float* bb = mat ? b_r : b_l;
    bf16* dst = mat ? xr : xl;
    const int c0 = cg * 4, nb = ng * 8;
    float acc[4][8];
    #pragma unroll
    for (int c = 0; c < 4; ++c)
        #pragma unroll
        for (int n = 0; n < 8; ++n) acc[c][n] = 0.f;
    for (int k = 0; k < 128; ++k) {
        float4 w = *(const float4*)(W + k * 128 + c0);
        #pragma unroll
        for (int n = 0; n < 8; ++n) {
            float xv = s_x[nb + n][k];
            acc[0][n] += xv * w.x;
            acc[1][n] += xv * w.y;
            acc[2][n] += xv * w.z;
            acc[3][n] += xv * w.w;
        }
    }
    float4 bv = *(const float4*)(bb + c0);
    for (int n = 0; n < 8; ++n) {
        int node = n0 + nb + n;
        if (node < NODES) {
            uint2 u;
            u.x = pack2(acc[0][n] + bv.x, acc[1][n] + bv.y);
            u.y = pack2(acc[2][n] + bv.z, acc[3][n] + bv.w);
            *(uint2*)(dst + node * 128 + c0) = u;
        }
    }
}

// ---------------------------------------------------------------------------
// Multi-block scan (replaces single-block k_scan, was 105 us on 1 CU).
// k_scan1: per-block sums of 1024-int chunks -> bsum[b]
// k_scan2: 1 wave scans the 49 block sums in-register -> exclusive offsets
//          (in place) + off[NODES] = total
// k_scan3: block-local exclusive scan + bsum[b] base -> off[i], cursor[i]
// ---------------------------------------------------------------------------
__global__ __launch_bounds__(256) void k_scan1(const int* count, int* bsum) {
    __shared__ int s_w[4];
    const int t = threadIdx.x, b = blockIdx.x;
    const int base = b * SCHUNK + t * 4;
    int s = 0;
    #pragma unroll
    for (int e = 0; e < 4; ++e) {
        int i = base + e;
        if (i < NODES) s += count[i];
    }
    #pragma unroll
    for (int d = 1; d < 64; d <<= 1) s += __shfl_xor(s, d, 64);
    if ((t & 63) == 0) s_w[t >> 6] = s;
    __syncthreads();
    if (t == 0) bsum[b] = s_w[0] + s_w[1] + s_w[2] + s_w[3];
}

__global__ __launch_bounds__(64) void k_scan2(int* bsum, int* off) {
    const int t = threadIdx.x;
    int v = (t < SBLK) ? bsum[t] : 0;
    int inc = v;
    #pragma unroll
    for (int d = 1; d < 64; d <<= 1) {
        int y = __shfl_up(inc, d, 64);
        if (t >= d) inc += y;
    }
    if (t < SBLK) bsum[t] = inc - v;     // exclusive
    if (t == 63) off[NODES] = inc;       // grand total
}

__global__ __launch_bounds__(256) void k_scan3(const int* count, const int* bsum,
                                               int* off, int* cursor) {
    __shared__ int s_w[4];
    const int t = threadIdx.x, b = blockIdx.x;
    const int lane = t & 63, wv = t >> 6;
    const int base = b * SCHUNK + t * 4;
    int v[4];
    int s = 0;
    #pragma unroll
    for (int e = 0; e < 4; ++e) {
        int i = base + e;
        v[e] = (i < NODES) ? count[i] : 0;
        s += v[e];
    }
    // wave-level inclusive scan of per-thread sums
    int inc = s;
    #pragma unroll
    for (int d = 1; d < 64; d <<= 1) {
        int y = __shfl_up(inc, d, 64);
        if (lane >= d) inc += y;
    }
    if (lane == 63) s_w[wv] = inc;       // wave total
    __syncthreads();
    int woff = 0;
    #pragma unroll
    for (int w = 0; w < 4; ++w) if (w < wv) woff += s_w[w];
    int run = bsum[b] + woff + (inc - s); // exclusive base for this thread
    #pragma unroll
    for (int e = 0; e < 4; ++e) {
        int i = base + e;
        if (i < NODES) { off[i] = run; cursor[i] = run; run += v[e]; }
    }
}

// ---------------------------------------------------------------------------
// k_wconv: transpose FFN weights to [col][k] and split into hi/lo bf16 pairs
// (hi = bf16(w), lo = bf16(w - hi)). Runs AFTER k_place so both the `count`
// and `cursor` workspace regions are dead and can hold the 4 arrays.
// ---------------------------------------------------------------------------
__global__ __launch_bounds__(256) void k_wconv(const float* W1, const float* W2,
                                               bf16* w1h, bf16* w1l,
                                               bf16* w2h, bf16* w2l) {
    int tid = blockIdx.x * blockDim.x + threadIdx.x;   // 65536 threads
    if (tid < 32768) {
        int c = tid >> 7, k = tid & 127;               // w1t[c][k]
        float v = W1[k * 256 + c];
        unsigned short hb = bfbits(v);
        float hv = __uint_as_float((unsigned int)hb << 16);
        w1h[tid] = f2bf(v);
        w1l[tid] = f2bf(v - hv);
    } else {
        int t = tid - 32768;
        int c = t >> 8, k = t & 255;                   // w2t[c][k]
        float v = W2[k * 128 + c];
        unsigned short hb = bfbits(v);
        float hv = __uint_as_float((unsigned int)hb << 16);
        w2h[t] = f2bf(v);
        w2l[t] = f2bf(v - hv);
    }
}

// ---------------------------------------------------------------------------
// k_place: perm[pos] = (ea_bf16_bits << 16) | src, grouped by dst.
// [byte-identical to passing R10]
// ---------------------------------------------------------------------------
__global__ __launch_bounds__(256) void k_place(const int* ei, const float* edge_attr,
                                               const float* sum_ea,
                                               int* cursor, unsigned int* perm) {
    const float meanv = sum_ea[0] * (1.f / (float)NEDGE);
    int tid = blockIdx.x * blockDim.x + threadIdx.x;
    int stride = gridDim.x * blockDim.x;
    for (int e = tid; e < ETOT; e += stride) {
        int src, dst; float eav;
        if (e < NEDGE) { src = ei[e]; dst = ei[NEDGE + e]; eav = edge_attr[e]; }
        else           { src = e - NEDGE; dst = src; eav = meanv; }
        int pos = atomicAdd(&cursor[dst], 1);
        perm[pos] = ((unsigned int)bfbits(eav) << 16) | (unsigned int)src;
    }
}

// ---------------------------------------------------------------------------
// k_agg: [byte-identical to passing R10]
// ---------------------------------------------------------------------------
__global__ __launch_bounds__(256) void k_agg(const unsigned int* xl32,
                                             const unsigned int* xr32,
                                             const unsigned int* perm, const int* off,
                                             const float* W_e, const float* att,
                                             float* outp) {
    const int lane = threadIdx.x & 63;
    const int wave0 = blockIdx.x * 4 + (threadIdx.x >> 6);
    const int nwaves = gridDim.x * 4;
    const int c = 2 * lane;
    const float we1 = W_e[c], we2 = W_e[c + 1];
    const float a1 = att[c], a2 = att[c + 1];
    for (int n = wave0; n < NODES; n += nwaves) {
        unsigned int xru = xr32[n * 64 + lane];
        float xr1 = bflo(xru), xr2 = bfhi(xru);
        int s0 = off[n], s1 = off[n + 1];
        float m = -1e30f, l = 0.f, acc1 = 0.f, acc2 = 0.f;
        int j = s0;
        for (; j + 4 <= s1; j += 4) {
            unsigned int u0 = perm[j];
            unsigned int u1 = perm[j + 1];
            unsigned int u2 = perm[j + 2];
            unsigned int u3 = perm[j + 3];
            unsigned int g0 = xl32[(u0 & 0xffffu) * 64 + lane];
            unsigned int g1 = xl32[(u1 & 0xffffu) * 64 + lane];
            unsigned int g2 = xl32[(u2 & 0xffffu) * 64 + lane];
            unsigned int g3 = xl32[(u3 & 0xffffu) * 64 + lane];
            float e0 = bfhi(u0), e1 = bfhi(u1), e2 = bfhi(u2), e3 = bfhi(u3);
            float x01 = bflo(g0), x02 = bfhi(g0);
            float x11 = bflo(g1), x12 = bfhi(g1);
            float x21 = bflo(g2), x22 = bfhi(g2);
            float x31 = bflo(g3), x32 = bfhi(g3);
            float p0, p1, p2, p3;
            {
                float v1 = x01 + xr1 + e0 * we1, v2 = x02 + xr2 + e0 * we2;
                v1 = (v1 > 0.f) ? v1 : 0.2f * v1;
                v2 = (v2 > 0.f) ? v2 : 0.2f * v2;
                p0 = v1 * a1 + v2 * a2;
            }
            {
                float v1 = x11 + xr1 + e1 * we1, v2 = x12 + xr2 + e1 * we2;
                v1 = (v1 > 0.f) ? v1 : 0.2f * v1;
                v2 = (v2 > 0.f) ? v2 : 0.2f * v2;
                p1 = v1 * a1 + v2 * a2;
            }
            {
                float v1 = x21 + xr1 + e2 * we1, v2 = x22 + xr2 + e2 * we2;
                v1 = (v1 > 0.f) ? v1 : 0.2f * v1;
                v2 = (v2 > 0.f) ? v2 : 0.2f * v2;
                p2 = v1 * a1 + v2 * a2;
            }
            {
                float v1 = x31 + xr1 + e3 * we1, v2 = x32 + xr2 + e3 * we2;
                v1 = (v1 > 0.f) ? v1 : 0.2f * v1;
                v2 = (v2 > 0.f) ? v2 : 0.2f * v2;
                p3 = v1 * a1 + v2 * a2;
            }
            p0 += __shfl_xor(p0, 1, 64); p1 += __shfl_xor(p1, 1, 64);
            p2 += __shfl_xor(p2, 1, 64); p3 += __shfl_xor(p3, 1, 64);
            p0 += __shfl_xor(p0, 2, 64); p1 += __shfl_xor(p1, 2, 64);
            p2 += __shfl_xor(p2, 2, 64); p3 += __shfl_xor(p3, 2, 64);
            p0 += __shfl_xor(p0, 4, 64); p1 += __shfl_xor(p1, 4, 64);
            p2 += __shfl_xor(p2, 4, 64); p3 += __shfl_xor(p3, 4, 64);
            p0 += __shfl_xor(p0, 8, 64); p1 += __shfl_xor(p1, 8, 64);
            p2 += __shfl_xor(p2, 8, 64); p3 += __shfl_xor(p3, 8, 64);
            float nm = fmaxf(fmaxf(m, fmaxf(p0, p1)), fmaxf(p2, p3));
            float sc = __expf(m - nm);
            float E0 = __expf(p0 - nm);
            float E1 = __expf(p1 - nm);
            float E2 = __expf(p2 - nm);
            float E3 = __expf(p3 - nm);
            l = l * sc + E0 + E1 + E2 + E3;
            acc1 = acc1 * sc + E0 * x01 + E1 * x11 + E2 * x21 + E3 * x31;
            acc2 = acc2 * sc + E0 * x02 + E1 * x12 + E2 * x22 + E3 * x32;
            m = nm;
        }
        for (; j < s1; ++j) {
            unsigned int u0 = perm[j];
            unsigned int g0 = xl32[(u0 & 0xffffu) * 64 + lane];
            float e0 = bfhi(u0);
            float x01 = bflo(g0), x02 = bfhi(g0);
            float v1 = x01 + xr1 + e0 * we1, v2 = x02 + xr2 + e0 * we2;
            v1 = (v1 > 0.f) ? v1 : 0.2f * v1;
            v2 = (v2 > 0.f) ? v2 : 0.2f * v2;
            float p = v1 * a1 + v2 * a2;
            p += __shfl_xor(p, 1, 64);
            p += __shfl_xor(p, 2, 64);
            p += __shfl_xor(p, 4, 64);
            p += __shfl_xor(p, 8, 64);
            float nm = fmaxf(m, p);
            float sc = __expf(m - nm);
            float ee = __expf(p - nm);
            l = l * sc + ee;
            acc1 = acc1 * sc + ee * x01;
            acc2 = acc2 * sc + ee * x02;
            m = nm;
        }
        float inv = 1.f / fmaxf(l, 1e-30f);
        *(float2*)(outp + n * 128 + c) = make_float2(acc1 * inv, acc2 * inv);
    }
}

// ---------------------------------------------------------------------------
// k_epi (split-precision MFMA): FFN1/FFN2 via mfma_f32_16x16x32_bf16 with
// hi/lo bf16 operand splits: A*B ~= Ah*Bh + Ah*Bl + Al*Bh (near-fp32).
// [byte-identical to passing R2]
// ---------------------------------------------------------------------------
__global__ __launch_bounds__(256) void k_epi(const float* out_agg, const float* x,
                                             const float* bias_out,
                                             const float* W_gate, const float* b_gate,
                                             const bf16* w1h, const bf16* w1l,
                                             const float* b_ffn1,
                                             const bf16* w2h, const bf16* w2l,
                                             const float* b_ffn2,
                                             const float* gamma, const float* beta,
                                             float* out) {
    __shared__ __align__(16) float s_y[32][132];   // h, then y (fp32; residual+LN+FFN1 A)
    __shared__ __align__(16) float s_t[32][260];   // relu(ffn1) fp32 (FFN2 A)
    __shared__ float s_g[32];
    __shared__ float s_mu[32], s_rs[32];
    const int tid = threadIdx.x;
    const int n0 = blockIdx.x * 32;
    int nn = NODES - n0; if (nn > 32) nn = 32;

    // phase 1: h = elu(out_agg + bias_out) -> s_y
    for (int it = 0; it < 4; ++it) {
        int idx4 = (it * 256 + tid) * 4;
        int n = idx4 >> 7, j = idx4 & 127;
        float4 w = make_float4(0.f, 0.f, 0.f, 0.f);
        if (n < nn) {
            float4 v  = *(const float4*)(out_agg + (n0 + n) * 128 + j);
            float4 bv = *(const float4*)(bias_out + j);
            float t0 = v.x + bv.x, t1 = v.y + bv.y;
            float t2 = v.z + bv.z, t3 = v.w + bv.w;
            w.x = (t0 > 0.f) ? t0 : (__expf(t0) - 1.f);
            w.y = (t1 > 0.f) ? t1 : (__expf(t1) - 1.f);
            w.z = (t2 > 0.f) ? t2 : (__expf(t2) - 1.f);
            w.w = (t3 > 0.f) ? t3 : (__expf(t3) - 1.f);
        }
        *(float4*)&s_y[n][j] = w;
    }
    __syncthreads();
    // gate: 8 threads per node, shfl-reduce within 8-lane groups
    {
        int n = tid >> 3, kb = (tid & 7) * 16;
        float g = 0.f;
        #pragma unroll
        for (int k = 0; k < 16; k += 4) {
            float4 w = *(const float4*)(W_gate + kb + k);
            float4 h = *(const float4*)&s_y[n][kb + k];
            g += h.x * w.x + h.y * w.y + h.z * w.z + h.w * w.w;
        }
        g += __shfl_xor(g, 1, 64);
        g += __shfl_xor(g, 2, 64);
        g += __shfl_xor(g, 4, 64);
        if ((tid & 7) == 0) s_g[n] = 1.f / (1.f + __expf(-(g + b_gate[0])));
    }
    __syncthreads();
    // y = g*h + (1-g)*x -> s_y (fp32)
    for (int it = 0; it < 4; ++it) {
        int idx4 = (it * 256 + tid) * 4;
        int n = idx4 >> 7, j = idx4 & 127;
        if (n < nn) {
            float g = s_g[n];
            float4 xv = *(const float4*)(x + (n0 + n) * 128 + j);
            float4 h = *(float4*)&s_y[n][j];
            h.x = g * h.x + (1.f - g) * xv.x;
            h.y = g * h.y + (1.f - g) * xv.y;
            h.z = g * h.z + (1.f - g) * xv.z;
            h.w = g * h.w + (1.f - g) * xv.w;
            *(float4*)&s_y[n][j] = h;
        }
    }
    __syncthreads();

    const int wv   = tid >> 6;          // wave 0..3
    const int ln   = tid & 63;
    const int lrow = ln & 15;           // A row / B,D col within tile
    const int lk8  = (ln >> 4) << 3;    // k chunk base: 0,8,16,24

    // FFN1: t = relu(y @ W1 + b1). M=32 (2 tiles), per-wave N=64 (4 tiles), K=128.
    f32x4 acc1[2][4];
    #pragma unroll
    for (int mt = 0; mt < 2; ++mt)
        #pragma unroll
        for (int i = 0; i < 4; ++i)
            acc1[mt][i] = (f32x4){0.f, 0.f, 0.f, 0.f};
    #pragma unroll
    for (int kk = 0; kk < 4; ++kk) {
        int k0 = kk * 32 + lk8;
        float a0f[8], a1f[8];
        *(float4*)&a0f[0] = *(const float4*)&s_y[lrow][k0];
        *(float4*)&a0f[4] = *(const float4*)&s_y[lrow][k0 + 4];
        *(float4*)&a1f[0] = *(const float4*)&s_y[16 + lrow][k0];
        *(float4*)&a1f[4] = *(const float4*)&s_y[16 + lrow][k0 + 4];
        bf16x8 a0h, a0l, a1h, a1l;
        split8(a0f, a0h, a0l);
        split8(a1f, a1h, a1l);
        #pragma unroll
        for (int i = 0; i < 4; ++i) {
            int col = (wv << 6) + (i << 4) + lrow;
            bf16x8 bh = *(const bf16x8*)(w1h + col * 128 + k0);
            bf16x8 bl = *(const bf16x8*)(w1l + col * 128 + k0);
            acc1[0][i] = __builtin_amdgcn_mfma_f32_16x16x32_bf16(a0l, bh, acc1[0][i], 0, 0, 0);
            acc1[0][i] = __builtin_amdgcn_mfma_f32_16x16x32_bf16(a0h, bl, acc1[0][i], 0, 0, 0);
            acc1[0][i] = __builtin_amdgcn_mfma_f32_16x16x32_bf16(a0h, bh, acc1[0][i], 0, 0, 0);
            acc1[1][i] = __builtin_amdgcn_mfma_f32_16x16x32_bf16(a1l, bh, acc1[1][i], 0, 0, 0);
            acc1[1][i] = __builtin_amdgcn_mfma_f32_16x16x32_bf16(a1h, bl, acc1[1][i], 0, 0, 0);
            acc1[1][i] = __builtin_amdgcn_mfma_f32_16x16x32_bf16(a1h, bh, acc1[1][i], 0, 0, 0);
        }
    }
    // epilogue: +b1, relu -> s_t (fp32; lanes 0-15 write consecutive cols)
    #pragma unroll
    for (int mt = 0; mt < 2; ++mt) {
        #pragma unroll
        for (int i = 0; i < 4; ++i) {
            int col = (wv << 6) + (i << 4) + lrow;
            float bv = b_ffn1[col];
            #pragma unroll
            for (int r = 0; r < 4; ++r) {
                int row = (mt << 4) + ((ln >> 4) << 2) + r;
                s_t[row][col] = fmaxf(acc1[mt][i][r] + bv, 0.f);
            }
        }
    }
    __syncthreads();

    // FFN2: ffn = t @ W2 + b2. M=32 (2 tiles), per-wave N=32 (2 tiles), K=256.
    f32x4 acc2[2][2];
    #pragma unroll
    for (int mt = 0; mt < 2; ++mt)
        #pragma unroll
        for (int c = 0; c < 2; ++c)
            acc2[mt][c] = (f32x4){0.f, 0.f, 0.f, 0.f};
    #pragma unroll
    for (int kk = 0; kk < 8; ++kk) {
        int k0 = kk * 32 + lk8;
        float a0f[8], a1f[8];
        *(float4*)&a0f[0] = *(const float4*)&s_t[lrow][k0];
        *(float4*)&a0f[4] = *(const float4*)&s_t[lrow][k0 + 4];
        *(float4*)&a1f[0] = *(const float4*)&s_t[16 + lrow][k0];
        *(float4*)&a1f[4] = *(const float4*)&s_t[16 + lrow][k0 + 4];
        bf16x8 a0h, a0l, a1h, a1l;
        split8(a0f, a0h, a0l);
        split8(a1f, a1h, a1l);
        #pragma unroll
        for (int c = 0; c < 2; ++c) {
            int col = (wv << 5) + (c << 4) + lrow;
            bf16x8 bh = *(const bf16x8*)(w2h + col * 256 + k0);
            bf16x8 bl = *(const bf16x8*)(w2l + col * 256 + k0);
            acc2[0][c] = __builtin_amdgcn_mfma_f32_16x16x32_bf16(a0l, bh, acc2[0][c], 0, 0, 0);
            acc2[0][c] = __builtin_amdgcn_mfma_f32_16x16x32_bf16(a0h, bl, acc2[0][c], 0, 0, 0);
            acc2[0][c] = __builtin_amdgcn_mfma_f32_16x16x32_bf16(a0h, bh, acc2[0][c], 0, 0, 0);
            acc2[1][c] = __builtin_amdgcn_mfma_f32_16x16x32_bf16(a1l, bh, acc2[1][c], 0, 0, 0);
            acc2[1][c] = __builtin_amdgcn_mfma_f32_16x16x32_bf16(a1h, bl, acc2[1][c], 0, 0, 0);
            acc2[1][c] = __builtin_amdgcn_mfma_f32_16x16x32_bf16(a1h, bh, acc2[1][c], 0, 0, 0);
        }
    }
    // epilogue: y += ffn + b2  (disjoint (row,col) per lane across block)
    #pragma unroll
    for (int mt = 0; mt < 2; ++mt) {
        #pragma unroll
        for (int c = 0; c < 2; ++c) {
            int col = (wv << 5) + (c << 4) + lrow;
            float bv = b_ffn2[col];
            #pragma unroll
            for (int r = 0; r < 4; ++r) {
                int row = (mt << 4) + ((ln >> 4) << 2) + r;
                s_y[row][col] += acc2[mt][c][r] + bv;
            }
        }
    }
    __syncthreads();
    // LayerNorm stats: 8 threads per node
    {
        int n = tid >> 3, kb = (tid & 7) * 16;
        float s = 0.f, ss = 0.f;
        #pragma unroll
        for (int k = 0; k < 16; k += 4) {
            float4 v = *(const float4*)&s_y[n][kb + k];
            s  += v.x + v.y + v.z + v.w;
            ss += v.x * v.x + v.y * v.y + v.z * v.z + v.w * v.w;
        }
        s  += __shfl_xor(s, 1, 64);  ss += __shfl_xor(ss, 1, 64);
        s  += __shfl_xor(s, 2, 64);  ss += __shfl_xor(ss, 2, 64);
        s  += __shfl_xor(s, 4, 64);  ss += __shfl_xor(ss, 4, 64);
        if ((tid & 7) == 0) {
            float mu = s * (1.f / 128.f);
            float var = ss * (1.f / 128.f) - mu * mu;
            s_mu[n] = mu;
            s_rs[n] = rsqrtf(fmaxf(var, 0.f) + 1e-5f);
        }
    }
    __syncthreads();
    // normalize + store (fp32)
    for (int it = 0; it < 4; ++it) {
        int idx4 = (it * 256 + tid) * 4;
        int n = idx4 >> 7, j = idx4 & 127;
        if (n < nn) {
            float mu = s_mu[n], rs = s_rs[n];
            float4 gv = *(const float4*)(gamma + j);
            float4 bv = *(const float4*)(beta + j);
            float4 v = *(const float4*)&s_y[n][j];
            float4 o;
            o.x = (v.x - mu) * rs * gv.x + bv.x;
            o.y = (v.y - mu) * rs * gv.y + bv.y;
            o.z = (v.z - mu) * rs * gv.z + bv.z;
            o.w = (v.w - mu) * rs * gv.w + bv.w;
            *(float4*)(out + (n0 + n) * 128 + j) = o;
        }
    }
}

// ---------------------------------------------------------------------------
extern "C" void kernel_launch(void* const* d_in, const int* in_sizes, int n_in,
                              void* d_out, int out_size, void* d_ws, size_t ws_size,
                              hipStream_t stream) {
    const float* x         = (const float*)d_in[0];
    const float* edge_attr = (const float*)d_in[1];
    const int* edge_index  = (const int*)d_in[17];
    float* out = (float*)d_out;

    char* base = (char*)d_ws;
    // workspace layout: EXACTLY the hardware-proven layout (29,600,064 B).
    float* sum_ea  = (float*)(base + 16);                     // 16
    int*   count   = (int*)  (base + 32);                     // 200000
    int*   off     = (int*)  (base + 200032);                 // 200004 (+pad)
    int*   cursor  = (int*)  (base + 400064);                 // 200000
    unsigned int* perm = (unsigned int*)(base + 600064);      // 3400000
    bf16*  xl      = (bf16*) (base + 4000064);                // 12800000
    bf16*  xr      = (bf16*) (base + 16800064);               // 12800000
    // scan block sums: head of perm region (dead until k_place, which runs
    // after k_scan3 in the serial stream). 49 ints.
    int*   bsum    = (int*)  (base + 600064);
    // split bf16 transposed FFN weights:
    //   w1 pair reuses `count` region (dead after k_scan3): 131072 B < 200000
    //   w2 pair reuses `cursor` region (dead after k_place): 131072 B < 200000
    bf16*  w1t_hi  = (bf16*) (base + 32);
    bf16*  w1t_lo  = (bf16*) (base + 32 + 65536);
    bf16*  w2t_hi  = (bf16*) (base + 400064);
    bf16*  w2t_lo  = (bf16*) (base + 400064 + 65536);

    hipMemsetAsync(sum_ea, 0, 16, stream);
    hipMemsetAsync(count, 0, NODES * sizeof(int), stream);

    const int NTILES = (NODES + 31) / 32;  // 1563

    k_prep  <<<1024, 256, 0, stream>>>(edge_attr, edge_index, sum_ea, count);
    k_xform <<<NTILES, 256, 0, stream>>>(x, (const float*)d_in[2], (const float*)d_in[3],
                                         (const float*)d_in[4], (const float*)d_in[5],
                                         xl, xr);
    k_scan1 <<<SBLK, 256, 0, stream>>>(count, bsum);
    k_scan2 <<<1, 64, 0, stream>>>(bsum, off);
    k_scan3 <<<SBLK, 256, 0, stream>>>(count, bsum, off, cursor);
    k_place <<<1024, 256, 0, stream>>>(edge_index, edge_attr, sum_ea, cursor, perm);
    k_wconv <<<256, 256, 0, stream>>>((const float*)d_in[11], (const float*)d_in[13],
                                      w1t_hi, w1t_lo, w2t_hi, w2t_lo);
    k_agg   <<<3125, 256, 0, stream>>>((const unsigned int*)xl,
                                       (const unsigned int*)xr,
                                       perm, off,
                                       (const float*)d_in[6], (const float*)d_in[7],
                                       out);
    k_epi   <<<NTILES, 256, 0, stream>>>(out, x, (const float*)d_in[8],
                                         (const float*)d_in[9], (const float*)d_in[10],
                                         w1t_hi, w1t_lo, (const float*)d_in[12],
                                         w2t_hi, w2t_lo, (const float*)d_in[14],
                                         (const float*)d_in[15], (const float*)d_in[16],
                                         out);
}

// Round 5
// 395.998 us; speedup vs baseline: 1.4228x; 1.0959x over previous
//
#include <hip/hip_runtime.h>
#include <hip/hip_bf16.h>

#define NODES 50000
#define NEDGE 800000
#define ETOT  850000   /* NEDGE + NODES self loops */

#define SCHUNK 1024
#define SBLK   ((NODES + SCHUNK - 1) / SCHUNK)   /* 49 */

#define XF_TILES 1563      /* ceil(NODES/32) */
#define PREP_BLKS 1024
#define FUSE_GRID 2587     /* 2*1024 interleaved + (1563-1024) tail */

typedef __hip_bfloat16 bf16;
typedef __attribute__((ext_vector_type(8))) short bf16x8;
typedef __attribute__((ext_vector_type(4))) float f32x4;

__device__ __forceinline__ bf16 f2bf(float v) { return __float2bfloat16(v); }
__device__ __forceinline__ float bflo(unsigned int v) { return __uint_as_float(v << 16); }
__device__ __forceinline__ float bfhi(unsigned int v) { return __uint_as_float(v & 0xffff0000u); }

__device__ __forceinline__ unsigned int pack2(float a, float b) {
    bf16 x = f2bf(a), y = f2bf(b);
    unsigned short xs = *reinterpret_cast<unsigned short*>(&x);
    unsigned short ys = *reinterpret_cast<unsigned short*>(&y);
    return ((unsigned int)ys << 16) | (unsigned int)xs;
}

__device__ __forceinline__ unsigned short bfbits(float v) {
    bf16 x = f2bf(v);
    return *reinterpret_cast<unsigned short*>(&x);
}

// split 8 fp32 -> hi/lo bf16x8 (Dekker split: lo = v - float(hi), exact)
__device__ __forceinline__ void split8(const float* v, bf16x8& hi, bf16x8& lo) {
    #pragma unroll
    for (int e = 0; e < 8; ++e) {
        unsigned short hb = bfbits(v[e]);
        float hv = __uint_as_float((unsigned int)hb << 16);
        unsigned short lb = bfbits(v[e] - hv);
        ((short*)&hi)[e] = (short)hb;
        ((short*)&lo)[e] = (short)lb;
    }
}

// ---------------------------------------------------------------------------
// k_fuse: grid-partitioned fusion of k_prep (atomic histogram + edge_attr
// sum; latency-bound, 0.7% VALU standalone) with k_xform (xl/xr transforms;
// compute-bound). Independent inputs/outputs. Odd bids < 2048 run prep so
// both roles are co-resident on every CU and xform's VALU work hides the
// atomic drain that made k_prep a 77 us standalone stall.
// ---------------------------------------------------------------------------
__global__ __launch_bounds__(256) void k_fuse(const float* edge_attr, const int* ei,
                                              float* sum_ea, int* count,
                                              const float* x,
                                              const float* W_l, const float* b_l,
                                              const float* W_r, const float* b_r,
                                              bf16* xl, bf16* xr) {
    __shared__ __align__(16) float s_x[32][132];
    const int bid = blockIdx.x;
    int idx;
    bool isprep;
    if (bid < 2 * PREP_BLKS) { isprep = (bid & 1); idx = bid >> 1; }
    else { isprep = false; idx = PREP_BLKS + (bid - 2 * PREP_BLKS); }

    if (isprep) {
        // --- prep role (block-uniform branch) ---
        int tid = idx * 256 + threadIdx.x;
        const int stride = PREP_BLKS * 256;
        float local = 0.f;
        for (int e = tid; e < ETOT; e += stride) {
            int dst = (e < NEDGE) ? ei[NEDGE + e] : (e - NEDGE);
            atomicAdd(&count[dst], 1);
            if (e < NEDGE) local += edge_attr[e];
        }
        #pragma unroll
        for (int s = 1; s < 64; s <<= 1) local += __shfl_xor(local, s, 64);
        if ((threadIdx.x & 63) == 0) atomicAdd(sum_ea, local);
        return;
    }

    // --- xform role [body identical to passing k_xform] ---
    const int tid = threadIdx.x;
    const int n0 = idx * 32;
    for (int it = 0; it < 4; ++it) {
        int idx4 = (it * 256 + tid) * 4;
        int n = idx4 >> 7, j = idx4 & 127;
        int node = n0 + n;
        float4 v = make_float4(0.f, 0.f, 0.f, 0.f);
        if (node < NODES) v = *(const float4*)(x + node * 128 + j);
        *(float4*)&s_x[n][j] = v;
    }
    __syncthreads();
    const int mat = tid >> 7;
    const int ng  = (tid >> 5) & 3;
    const int cg  = tid & 31;
    const float* W  = mat ? W_r : W_l;
    const float* bb = mat ? b_r : b_l;
    bf16* dst = mat ? xr : xl;
    const int c0 = cg * 4, nb = ng * 8;
    float acc[4][8];
    #pragma unroll
    for (int c = 0; c < 4; ++c)
        #pragma unroll
        for (int n = 0; n < 8; ++n) acc[c][n] = 0.f;
    for (int k = 0; k < 128; ++k) {
        float4 w = *(const float4*)(W + k * 128 + c0);
        #pragma unroll
        for (int n = 0; n < 8; ++n) {
            float xv = s_x[nb + n][k];
            acc[0][n] += xv * w.x;
            acc[1][n] += xv * w.y;
            acc[2][n] += xv * w.z;
            acc[3][n] += xv * w.w;
        }
    }
    float4 bv = *(const float4*)(bb + c0);
    for (int n = 0; n < 8; ++n) {
        int node = n0 + nb + n;
        if (node < NODES) {
            uint2 u;
            u.x = pack2(acc[0][n] + bv.x, acc[1][n] + bv.y);
            u.y = pack2(acc[2][n] + bv.z, acc[3][n] + bv.w);
            *(uint2*)(dst + node * 128 + c0) = u;
        }
    }
}

// ---------------------------------------------------------------------------
// Multi-block scan. k_scan1: per-block sums of 1024-int chunks -> bsum[b].
// k_scan3: computes its block base by wave-reducing bsum[j<b] in-kernel
// (absorbs the old k_scan2 launch), then block-local exclusive scan ->
// off[i], cursor[i]; last thread writes off[NODES] = grand total.
// ---------------------------------------------------------------------------
__global__ __launch_bounds__(256) void k_scan1(const int* count, int* bsum) {
    __shared__ int s_w[4];
    const int t = threadIdx.x, b = blockIdx.x;
    const int base = b * SCHUNK + t * 4;
    int s = 0;
    #pragma unroll
    for (int e = 0; e < 4; ++e) {
        int i = base + e;
        if (i < NODES) s += count[i];
    }
    #pragma unroll
    for (int d = 1; d < 64; d <<= 1) s += __shfl_xor(s, d, 64);
    if ((t & 63) == 0) s_w[t >> 6] = s;
    __syncthreads();
    if (t == 0) bsum[b] = s_w[0] + s_w[1] + s_w[2] + s_w[3];
}

__global__ __launch_bounds__(256) void k_scan3(const int* count, const int* bsum,
                                               int* off, int* cursor) {
    __shared__ int s_w[4];
    __shared__ int s_base;
    const int t = threadIdx.x, b = blockIdx.x;
    const int lane = t & 63, wv = t >> 6;
    // block base = sum of bsum[j] for j < b (b <= 48 < 64, one wave does it)
    if (t < 64) {
        int v = (t < b) ? bsum[t] : 0;
        #pragma unroll
        for (int d = 1; d < 64; d <<= 1) v += __shfl_xor(v, d, 64);
        if (t == 0) s_base = v;
    }
    const int base = b * SCHUNK + t * 4;
    int v[4];
    int s = 0;
    #pragma unroll
    for (int e = 0; e < 4; ++e) {
        int i = base + e;
        v[e] = (i < NODES) ? count[i] : 0;
        s += v[e];
    }
    // wave-level inclusive scan of per-thread sums
    int inc = s;
    #pragma unroll
    for (int d = 1; d < 64; d <<= 1) {
        int y = __shfl_up(inc, d, 64);
        if (lane >= d) inc += y;
    }
    if (lane == 63) s_w[wv] = inc;       // wave total
    __syncthreads();
    int woff = 0;
    #pragma unroll
    for (int w = 0; w < 4; ++w) if (w < wv) woff += s_w[w];
    int run = s_base + woff + (inc - s); // exclusive base for this thread
    #pragma unroll
    for (int e = 0; e < 4; ++e) {
        int i = base + e;
        if (i < NODES) {
            off[i] = run; cursor[i] = run; run += v[e];
            if (i == NODES - 1) off[NODES] = run;   // grand total
        }
    }
}

// ---------------------------------------------------------------------------
// k_wconv: transpose FFN weights to [col][k] and split into hi/lo bf16 pairs
// (hi = bf16(w), lo = bf16(w - hi)). Runs AFTER k_place so both the `count`
// and `cursor` workspace regions are dead and can hold the 4 arrays.
// ---------------------------------------------------------------------------
__global__ __launch_bounds__(256) void k_wconv(const float* W1, const float* W2,
                                               bf16* w1h, bf16* w1l,
                                               bf16* w2h, bf16* w2l) {
    int tid = blockIdx.x * blockDim.x + threadIdx.x;   // 65536 threads
    if (tid < 32768) {
        int c = tid >> 7, k = tid & 127;               // w1t[c][k]
        float v = W1[k * 256 + c];
        unsigned short hb = bfbits(v);
        float hv = __uint_as_float((unsigned int)hb << 16);
        w1h[tid] = f2bf(v);
        w1l[tid] = f2bf(v - hv);
    } else {
        int t = tid - 32768;
        int c = t >> 8, k = t & 255;                   // w2t[c][k]
        float v = W2[k * 128 + c];
        unsigned short hb = bfbits(v);
        float hv = __uint_as_float((unsigned int)hb << 16);
        w2h[t] = f2bf(v);
        w2l[t] = f2bf(v - hv);
    }
}

// ---------------------------------------------------------------------------
// k_place: perm[pos] = (ea_bf16_bits << 16) | src, grouped by dst.
// [byte-identical to passing R10]
// ---------------------------------------------------------------------------
__global__ __launch_bounds__(256) void k_place(const int* ei, const float* edge_attr,
                                               const float* sum_ea,
                                               int* cursor, unsigned int* perm) {
    const float meanv = sum_ea[0] * (1.f / (float)NEDGE);
    int tid = blockIdx.x * blockDim.x + threadIdx.x;
    int stride = gridDim.x * blockDim.x;
    for (int e = tid; e < ETOT; e += stride) {
        int src, dst; float eav;
        if (e < NEDGE) { src = ei[e]; dst = ei[NEDGE + e]; eav = edge_attr[e]; }
        else           { src = e - NEDGE; dst = src; eav = meanv; }
        int pos = atomicAdd(&cursor[dst], 1);
        perm[pos] = ((unsigned int)bfbits(eav) << 16) | (unsigned int)src;
    }
}

// ---------------------------------------------------------------------------
// k_agg: [byte-identical to passing R10]
// ---------------------------------------------------------------------------
__global__ __launch_bounds__(256) void k_agg(const unsigned int* xl32,
                                             const unsigned int* xr32,
                                             const unsigned int* perm, const int* off,
                                             const float* W_e, const float* att,
                                             float* outp) {
    const int lane = threadIdx.x & 63;
    const int wave0 = blockIdx.x * 4 + (threadIdx.x >> 6);
    const int nwaves = gridDim.x * 4;
    const int c = 2 * lane;
    const float we1 = W_e[c], we2 = W_e[c + 1];
    const float a1 = att[c], a2 = att[c + 1];
    for (int n = wave0; n < NODES; n += nwaves) {
        unsigned int xru = xr32[n * 64 + lane];
        float xr1 = bflo(xru), xr2 = bfhi(xru);
        int s0 = off[n], s1 = off[n + 1];
        float m = -1e30f, l = 0.f, acc1 = 0.f, acc2 = 0.f;
        int j = s0;
        for (; j + 4 <= s1; j += 4) {
            unsigned int u0 = perm[j];
            unsigned int u1 = perm[j + 1];
            unsigned int u2 = perm[j + 2];
            unsigned int u3 = perm[j + 3];
            unsigned int g0 = xl32[(u0 & 0xffffu) * 64 + lane];
            unsigned int g1 = xl32[(u1 & 0xffffu) * 64 + lane];
            unsigned int g2 = xl32[(u2 & 0xffffu) * 64 + lane];
            unsigned int g3 = xl32[(u3 & 0xffffu) * 64 + lane];
            float e0 = bfhi(u0), e1 = bfhi(u1), e2 = bfhi(u2), e3 = bfhi(u3);
            float x01 = bflo(g0), x02 = bfhi(g0);
            float x11 = bflo(g1), x12 = bfhi(g1);
            float x21 = bflo(g2), x22 = bfhi(g2);
            float x31 = bflo(g3), x32 = bfhi(g3);
            float p0, p1, p2, p3;
            {
                float v1 = x01 + xr1 + e0 * we1, v2 = x02 + xr2 + e0 * we2;
                v1 = (v1 > 0.f) ? v1 : 0.2f * v1;
                v2 = (v2 > 0.f) ? v2 : 0.2f * v2;
                p0 = v1 * a1 + v2 * a2;
            }
            {
                float v1 = x11 + xr1 + e1 * we1, v2 = x12 + xr2 + e1 * we2;
                v1 = (v1 > 0.f) ? v1 : 0.2f * v1;
                v2 = (v2 > 0.f) ? v2 : 0.2f * v2;
                p1 = v1 * a1 + v2 * a2;
            }
            {
                float v1 = x21 + xr1 + e2 * we1, v2 = x22 + xr2 + e2 * we2;
                v1 = (v1 > 0.f) ? v1 : 0.2f * v1;
                v2 = (v2 > 0.f) ? v2 : 0.2f * v2;
                p2 = v1 * a1 + v2 * a2;
            }
            {
                float v1 = x31 + xr1 + e3 * we1, v2 = x32 + xr2 + e3 * we2;
                v1 = (v1 > 0.f) ? v1 : 0.2f * v1;
                v2 = (v2 > 0.f) ? v2 : 0.2f * v2;
                p3 = v1 * a1 + v2 * a2;
            }
            p0 += __shfl_xor(p0, 1, 64); p1 += __shfl_xor(p1, 1, 64);
            p2 += __shfl_xor(p2, 1, 64); p3 += __shfl_xor(p3, 1, 64);
            p0 += __shfl_xor(p0, 2, 64); p1 += __shfl_xor(p1, 2, 64);
            p2 += __shfl_xor(p2, 2, 64); p3 += __shfl_xor(p3, 2, 64);
            p0 += __shfl_xor(p0, 4, 64); p1 += __shfl_xor(p1, 4, 64);
            p2 += __shfl_xor(p2, 4, 64); p3 += __shfl_xor(p3, 4, 64);
            p0 += __shfl_xor(p0, 8, 64); p1 += __shfl_xor(p1, 8, 64);
            p2 += __shfl_xor(p2, 8, 64); p3 += __shfl_xor(p3, 8, 64);
            float nm = fmaxf(fmaxf(m, fmaxf(p0, p1)), fmaxf(p2, p3));
            float sc = __expf(m - nm);
            float E0 = __expf(p0 - nm);
            float E1 = __expf(p1 - nm);
            float E2 = __expf(p2 - nm);
            float E3 = __expf(p3 - nm);
            l = l * sc + E0 + E1 + E2 + E3;
            acc1 = acc1 * sc + E0 * x01 + E1 * x11 + E2 * x21 + E3 * x31;
            acc2 = acc2 * sc + E0 * x02 + E1 * x12 + E2 * x22 + E3 * x32;
            m = nm;
        }
        for (; j < s1; ++j) {
            unsigned int u0 = perm[j];
            unsigned int g0 = xl32[(u0 & 0xffffu) * 64 + lane];
            float e0 = bfhi(u0);
            float x01 = bflo(g0), x02 = bfhi(g0);
            float v1 = x01 + xr1 + e0 * we1, v2 = x02 + xr2 + e0 * we2;
            v1 = (v1 > 0.f) ? v1 : 0.2f * v1;
            v2 = (v2 > 0.f) ? v2 : 0.2f * v2;
            float p = v1 * a1 + v2 * a2;
            p += __shfl_xor(p, 1, 64);
            p += __shfl_xor(p, 2, 64);
            p += __shfl_xor(p, 4, 64);
            p += __shfl_xor(p, 8, 64);
            float nm = fmaxf(m, p);
            float sc = __expf(m - nm);
            float ee = __expf(p - nm);
            l = l * sc + ee;
            acc1 = acc1 * sc + ee * x01;
            acc2 = acc2 * sc + ee * x02;
            m = nm;
        }
        float inv = 1.f / fmaxf(l, 1e-30f);
        *(float2*)(outp + n * 128 + c) = make_float2(acc1 * inv, acc2 * inv);
    }
}

// ---------------------------------------------------------------------------
// k_epi (split-precision MFMA): FFN1/FFN2 via mfma_f32_16x16x32_bf16 with
// hi/lo bf16 operand splits: A*B ~= Ah*Bh + Ah*Bl + Al*Bh (near-fp32).
// [byte-identical to passing R2]
// ---------------------------------------------------------------------------
__global__ __launch_bounds__(256) void k_epi(const float* out_agg, const float* x,
                                             const float* bias_out,
                                             const float* W_gate, const float* b_gate,
                                             const bf16* w1h, const bf16* w1l,
                                             const float* b_ffn1,
                                             const bf16* w2h, const bf16* w2l,
                                             const float* b_ffn2,
                                             const float* gamma, const float* beta,
                                             float* out) {
    __shared__ __align__(16) float s_y[32][132];   // h, then y (fp32; residual+LN+FFN1 A)
    __shared__ __align__(16) float s_t[32][260];   // relu(ffn1) fp32 (FFN2 A)
    __shared__ float s_g[32];
    __shared__ float s_mu[32], s_rs[32];
    const int tid = threadIdx.x;
    const int n0 = blockIdx.x * 32;
    int nn = NODES - n0; if (nn > 32) nn = 32;

    // phase 1: h = elu(out_agg + bias_out) -> s_y
    for (int it = 0; it < 4; ++it) {
        int idx4 = (it * 256 + tid) * 4;
        int n = idx4 >> 7, j = idx4 & 127;
        float4 w = make_float4(0.f, 0.f, 0.f, 0.f);
        if (n < nn) {
            float4 v  = *(const float4*)(out_agg + (n0 + n) * 128 + j);
            float4 bv = *(const float4*)(bias_out + j);
            float t0 = v.x + bv.x, t1 = v.y + bv.y;
            float t2 = v.z + bv.z, t3 = v.w + bv.w;
            w.x = (t0 > 0.f) ? t0 : (__expf(t0) - 1.f);
            w.y = (t1 > 0.f) ? t1 : (__expf(t1) - 1.f);
            w.z = (t2 > 0.f) ? t2 : (__expf(t2) - 1.f);
            w.w = (t3 > 0.f) ? t3 : (__expf(t3) - 1.f);
        }
        *(float4*)&s_y[n][j] = w;
    }
    __syncthreads();
    // gate: 8 threads per node, shfl-reduce within 8-lane groups
    {
        int n = tid >> 3, kb = (tid & 7) * 16;
        float g = 0.f;
        #pragma unroll
        for (int k = 0; k < 16; k += 4) {
            float4 w = *(const float4*)(W_gate + kb + k);
            float4 h = *(const float4*)&s_y[n][kb + k];
            g += h.x * w.x + h.y * w.y + h.z * w.z + h.w * w.w;
        }
        g += __shfl_xor(g, 1, 64);
        g += __shfl_xor(g, 2, 64);
        g += __shfl_xor(g, 4, 64);
        if ((tid & 7) == 0) s_g[n] = 1.f / (1.f + __expf(-(g + b_gate[0])));
    }
    __syncthreads();
    // y = g*h + (1-g)*x -> s_y (fp32)
    for (int it = 0; it < 4; ++it) {
        int idx4 = (it * 256 + tid) * 4;
        int n = idx4 >> 7, j = idx4 & 127;
        if (n < nn) {
            float g = s_g[n];
            float4 xv = *(const float4*)(x + (n0 + n) * 128 + j);
            float4 h = *(float4*)&s_y[n][j];
            h.x = g * h.x + (1.f - g) * xv.x;
            h.y = g * h.y + (1.f - g) * xv.y;
            h.z = g * h.z + (1.f - g) * xv.z;
            h.w = g * h.w + (1.f - g) * xv.w;
            *(float4*)&s_y[n][j] = h;
        }
    }
    __syncthreads();

    const int wv   = tid >> 6;          // wave 0..3
    const int ln   = tid & 63;
    const int lrow = ln & 15;           // A row / B,D col within tile
    const int lk8  = (ln >> 4) << 3;    // k chunk base: 0,8,16,24

    // FFN1: t = relu(y @ W1 + b1). M=32 (2 tiles), per-wave N=64 (4 tiles), K=128.
    f32x4 acc1[2][4];
    #pragma unroll
    for (int mt = 0; mt < 2; ++mt)
        #pragma unroll
        for (int i = 0; i < 4; ++i)
            acc1[mt][i] = (f32x4){0.f, 0.f, 0.f, 0.f};
    #pragma unroll
    for (int kk = 0; kk < 4; ++kk) {
        int k0 = kk * 32 + lk8;
        float a0f[8], a1f[8];
        *(float4*)&a0f[0] = *(const float4*)&s_y[lrow][k0];
        *(float4*)&a0f[4] = *(const float4*)&s_y[lrow][k0 + 4];
        *(float4*)&a1f[0] = *(const float4*)&s_y[16 + lrow][k0];
        *(float4*)&a1f[4] = *(const float4*)&s_y[16 + lrow][k0 + 4];
        bf16x8 a0h, a0l, a1h, a1l;
        split8(a0f, a0h, a0l);
        split8(a1f, a1h, a1l);
        #pragma unroll
        for (int i = 0; i < 4; ++i) {
            int col = (wv << 6) + (i << 4) + lrow;
            bf16x8 bh = *(const bf16x8*)(w1h + col * 128 + k0);
            bf16x8 bl = *(const bf16x8*)(w1l + col * 128 + k0);
            acc1[0][i] = __builtin_amdgcn_mfma_f32_16x16x32_bf16(a0l, bh, acc1[0][i], 0, 0, 0);
            acc1[0][i] = __builtin_amdgcn_mfma_f32_16x16x32_bf16(a0h, bl, acc1[0][i], 0, 0, 0);
            acc1[0][i] = __builtin_amdgcn_mfma_f32_16x16x32_bf16(a0h, bh, acc1[0][i], 0, 0, 0);
            acc1[1][i] = __builtin_amdgcn_mfma_f32_16x16x32_bf16(a1l, bh, acc1[1][i], 0, 0, 0);
            acc1[1][i] = __builtin_amdgcn_mfma_f32_16x16x32_bf16(a1h, bl, acc1[1][i], 0, 0, 0);
            acc1[1][i] = __builtin_amdgcn_mfma_f32_16x16x32_bf16(a1h, bh, acc1[1][i], 0, 0, 0);
        }
    }
    // epilogue: +b1, relu -> s_t (fp32; lanes 0-15 write consecutive cols)
    #pragma unroll
    for (int mt = 0; mt < 2; ++mt) {
        #pragma unroll
        for (int i = 0; i < 4; ++i) {
            int col = (wv << 6) + (i << 4) + lrow;
            float bv = b_ffn1[col];
            #pragma unroll
            for (int r = 0; r < 4; ++r) {
                int row = (mt << 4) + ((ln >> 4) << 2) + r;
                s_t[row][col] = fmaxf(acc1[mt][i][r] + bv, 0.f);
            }
        }
    }
    __syncthreads();

    // FFN2: ffn = t @ W2 + b2. M=32 (2 tiles), per-wave N=32 (2 tiles), K=256.
    f32x4 acc2[2][2];
    #pragma unroll
    for (int mt = 0; mt < 2; ++mt)
        #pragma unroll
        for (int c = 0; c < 2; ++c)
            acc2[mt][c] = (f32x4){0.f, 0.f, 0.f, 0.f};
    #pragma unroll
    for (int kk = 0; kk < 8; ++kk) {
        int k0 = kk * 32 + lk8;
        float a0f[8], a1f[8];
        *(float4*)&a0f[0] = *(const float4*)&s_t[lrow][k0];
        *(float4*)&a0f[4] = *(const float4*)&s_t[lrow][k0 + 4];
        *(float4*)&a1f[0] = *(const float4*)&s_t[16 + lrow][k0];
        *(float4*)&a1f[4] = *(const float4*)&s_t[16 + lrow][k0 + 4];
        bf16x8 a0h, a0l, a1h, a1l;
        split8(a0f, a0h, a0l);
        split8(a1f, a1h, a1l);
        #pragma unroll
        for (int c = 0; c < 2; ++c) {
            int col = (wv << 5) + (c << 4) + lrow;
            bf16x8 bh = *(const bf16x8*)(w2h + col * 256 + k0);
            bf16x8 bl = *(const bf16x8*)(w2l + col * 256 + k0);
            acc2[0][c] = __builtin_amdgcn_mfma_f32_16x16x32_bf16(a0l, bh, acc2[0][c], 0, 0, 0);
            acc2[0][c] = __builtin_amdgcn_mfma_f32_16x16x32_bf16(a0h, bl, acc2[0][c], 0, 0, 0);
            acc2[0][c] = __builtin_amdgcn_mfma_f32_16x16x32_bf16(a0h, bh, acc2[0][c], 0, 0, 0);
            acc2[1][c] = __builtin_amdgcn_mfma_f32_16x16x32_bf16(a1l, bh, acc2[1][c], 0, 0, 0);
            acc2[1][c] = __builtin_amdgcn_mfma_f32_16x16x32_bf16(a1h, bl, acc2[1][c], 0, 0, 0);
            acc2[1][c] = __builtin_amdgcn_mfma_f32_16x16x32_bf16(a1h, bh, acc2[1][c], 0, 0, 0);
        }
    }
    // epilogue: y += ffn + b2  (disjoint (row,col) per lane across block)
    #pragma unroll
    for (int mt = 0; mt < 2; ++mt) {
        #pragma unroll
        for (int c = 0; c < 2; ++c) {
            int col = (wv << 5) + (c << 4) + lrow;
            float bv = b_ffn2[col];
            #pragma unroll
            for (int r = 0; r < 4; ++r) {
                int row = (mt << 4) + ((ln >> 4) << 2) + r;
                s_y[row][col] += acc2[mt][c][r] + bv;
            }
        }
    }
    __syncthreads();
    // LayerNorm stats: 8 threads per node
    {
        int n = tid >> 3, kb = (tid & 7) * 16;
        float s = 0.f, ss = 0.f;
        #pragma unroll
        for (int k = 0; k < 16; k += 4) {
            float4 v = *(const float4*)&s_y[n][kb + k];
            s  += v.x + v.y + v.z + v.w;
            ss += v.x * v.x + v.y * v.y + v.z * v.z + v.w * v.w;
        }
        s  += __shfl_xor(s, 1, 64);  ss += __shfl_xor(ss, 1, 64);
        s  += __shfl_xor(s, 2, 64);  ss += __shfl_xor(ss, 2, 64);
        s  += __shfl_xor(s, 4, 64);  ss += __shfl_xor(ss, 4, 64);
        if ((tid & 7) == 0) {
            float mu = s * (1.f / 128.f);
            float var = ss * (1.f / 128.f) - mu * mu;
            s_mu[n] = mu;
            s_rs[n] = rsqrtf(fmaxf(var, 0.f) + 1e-5f);
        }
    }
    __syncthreads();
    // normalize + store (fp32)
    for (int it = 0; it < 4; ++it) {
        int idx4 = (it * 256 + tid) * 4;
        int n = idx4 >> 7, j = idx4 & 127;
        if (n < nn) {
            float mu = s_mu[n], rs = s_rs[n];
            float4 gv = *(const float4*)(gamma + j);
            float4 bv = *(const float4*)(beta + j);
            float4 v = *(const float4*)&s_y[n][j];
            float4 o;
            o.x = (v.x - mu) * rs * gv.x + bv.x;
            o.y = (v.y - mu) * rs * gv.y + bv.y;
            o.z = (v.z - mu) * rs * gv.z + bv.z;
            o.w = (v.w - mu) * rs * gv.w + bv.w;
            *(float4*)(out + (n0 + n) * 128 + j) = o;
        }
    }
}

// ---------------------------------------------------------------------------
extern "C" void kernel_launch(void* const* d_in, const int* in_sizes, int n_in,
                              void* d_out, int out_size, void* d_ws, size_t ws_size,
                              hipStream_t stream) {
    const float* x         = (const float*)d_in[0];
    const float* edge_attr = (const float*)d_in[1];
    const int* edge_index  = (const int*)d_in[17];
    float* out = (float*)d_out;

    char* base = (char*)d_ws;
    // workspace layout: EXACTLY the hardware-proven layout (29,600,064 B).
    float* sum_ea  = (float*)(base + 16);                     // 16
    int*   count   = (int*)  (base + 32);                     // 200000
    int*   off     = (int*)  (base + 200032);                 // 200004 (+pad)
    int*   cursor  = (int*)  (base + 400064);                 // 200000
    unsigned int* perm = (unsigned int*)(base + 600064);      // 3400000
    bf16*  xl      = (bf16*) (base + 4000064);                // 12800000
    bf16*  xr      = (bf16*) (base + 16800064);               // 12800000
    // scan block sums: head of perm region (dead until k_place, which runs
    // after k_scan3 in the serial stream). 49 ints.
    int*   bsum    = (int*)  (base + 600064);
    // split bf16 transposed FFN weights:
    //   w1 pair reuses `count` region (dead after k_scan3): 131072 B < 200000
    //   w2 pair reuses `cursor` region (dead after k_place): 131072 B < 200000
    bf16*  w1t_hi  = (bf16*) (base + 32);
    bf16*  w1t_lo  = (bf16*) (base + 32 + 65536);
    bf16*  w2t_hi  = (bf16*) (base + 400064);
    bf16*  w2t_lo  = (bf16*) (base + 400064 + 65536);

    hipMemsetAsync(sum_ea, 0, 16, stream);
    hipMemsetAsync(count, 0, NODES * sizeof(int), stream);

    const int NTILES = (NODES + 31) / 32;  // 1563

    k_fuse  <<<FUSE_GRID, 256, 0, stream>>>(edge_attr, edge_index, sum_ea, count,
                                            x, (const float*)d_in[2], (const float*)d_in[3],
                                            (const float*)d_in[4], (const float*)d_in[5],
                                            xl, xr);
    k_scan1 <<<SBLK, 256, 0, stream>>>(count, bsum);
    k_scan3 <<<SBLK, 256, 0, stream>>>(count, bsum, off, cursor);
    k_place <<<1024, 256, 0, stream>>>(edge_index, edge_attr, sum_ea, cursor, perm);
    k_wconv <<<256, 256, 0, stream>>>((const float*)d_in[11], (const float*)d_in[13],
                                      w1t_hi, w1t_lo, w2t_hi, w2t_lo);
    k_agg   <<<3125, 256, 0, stream>>>((const unsigned int*)xl,
                                       (const unsigned int*)xr,
                                       perm, off,
                                       (const float*)d_in[6], (const float*)d_in[7],
                                       out);
    k_epi   <<<NTILES, 256, 0, stream>>>(out, x, (const float*)d_in[8],
                                         (const float*)d_in[9], (const float*)d_in[10],
                                         w1t_hi, w1t_lo, (const float*)d_in[12],
                                         w2t_hi, w2t_lo, (const float*)d_in[14],
                                         (const float*)d_in[15], (const float*)d_in[16],
                                         out);
}

// Round 6
// 350.496 us; speedup vs baseline: 1.6075x; 1.1298x over previous
//
#include <hip/hip_runtime.h>
#include <hip/hip_bf16.h>

#define NODES 50000
#define NEDGE 800000
#define ETOT  850000   /* NEDGE + NODES self loops */

#define SCHUNK 1024
#define SBLK   ((NODES + SCHUNK - 1) / SCHUNK)   /* 49 */

#define XF_TILES 1563      /* ceil(NODES/32) */
#define PREP_BLKS 1024
#define FUSE_GRID 2587     /* 2*1024 interleaved + (1563-1024) tail */

typedef __hip_bfloat16 bf16;
typedef __attribute__((ext_vector_type(8))) short bf16x8;
typedef __attribute__((ext_vector_type(4))) float f32x4;

__device__ __forceinline__ bf16 f2bf(float v) { return __float2bfloat16(v); }
__device__ __forceinline__ float bflo(unsigned int v) { return __uint_as_float(v << 16); }
__device__ __forceinline__ float bfhi(unsigned int v) { return __uint_as_float(v & 0xffff0000u); }

__device__ __forceinline__ unsigned int pack2(float a, float b) {
    bf16 x = f2bf(a), y = f2bf(b);
    unsigned short xs = *reinterpret_cast<unsigned short*>(&x);
    unsigned short ys = *reinterpret_cast<unsigned short*>(&y);
    return ((unsigned int)ys << 16) | (unsigned int)xs;
}

__device__ __forceinline__ unsigned short bfbits(float v) {
    bf16 x = f2bf(v);
    return *reinterpret_cast<unsigned short*>(&x);
}

// split 8 fp32 -> hi/lo bf16x8 (Dekker split: lo = v - float(hi), exact)
__device__ __forceinline__ void split8(const float* v, bf16x8& hi, bf16x8& lo) {
    #pragma unroll
    for (int e = 0; e < 8; ++e) {
        unsigned short hb = bfbits(v[e]);
        float hv = __uint_as_float((unsigned int)hb << 16);
        unsigned short lb = bfbits(v[e] - hv);
        ((short*)&hi)[e] = (short)hb;
        ((short*)&lo)[e] = (short)lb;
    }
}

// ---------------------------------------------------------------------------
// k_wxf: W_l/W_r [128k x 128c] -> transposed [c][k] hi/lo bf16 split pairs.
// Runs FIRST; outputs live in perm region (+1024), dead until k_place writes
// perm (k_fuse consumes them before that).
// ---------------------------------------------------------------------------
__global__ __launch_bounds__(256) void k_wxf(const float* W_l, const float* W_r,
                                             bf16* wlh, bf16* wll,
                                             bf16* wrh, bf16* wrl) {
    int tid = blockIdx.x * blockDim.x + threadIdx.x;   // 32768 threads
    int m = tid >> 14;
    int t = tid & 16383;
    int c = t >> 7, k = t & 127;
    const float* W = m ? W_r : W_l;
    float v = W[k * 128 + c];
    unsigned short hb = bfbits(v);
    float hv = __uint_as_float((unsigned int)hb << 16);
    bf16* dh = m ? wrh : wlh;
    bf16* dl = m ? wrl : wll;
    dh[t] = f2bf(v);
    dl[t] = f2bf(v - hv);
}

// ---------------------------------------------------------------------------
// k_fuse: grid-partitioned fusion of prep (atomic rank-assign histogram +
// edge_attr sum; latency/atomic-bound) with MFMA xform (split-precision
// bf16 MFMA, near-fp32). prep's atomicAdd now RETURNS the rank, stored to
// tmp_rank[e] (uchar, coalesced) so k_place needs no atomics at all.
// ---------------------------------------------------------------------------
__global__ __launch_bounds__(256) void k_fuse(const float* edge_attr, const int* ei,
                                              float* sum_ea, int* cnt,
                                              unsigned char* tmp_rank,
                                              const float* x,
                                              const bf16* wlh, const bf16* wll,
                                              const bf16* wrh, const bf16* wrl,
                                              const float* b_l, const float* b_r,
                                              bf16* xl, bf16* xr) {
    __shared__ __align__(16) float s_x[32][132];
    const int bid = blockIdx.x;
    int idx;
    bool isprep;
    if (bid < 2 * PREP_BLKS) { isprep = (bid & 1); idx = bid >> 1; }
    else { isprep = false; idx = PREP_BLKS + (bid - 2 * PREP_BLKS); }

    if (isprep) {
        // --- prep role (block-uniform branch; no barriers on this path) ---
        int tid = idx * 256 + threadIdx.x;
        const int stride = PREP_BLKS * 256;
        float local = 0.f;
        for (int e = tid; e < ETOT; e += stride) {
            int dst = (e < NEDGE) ? ei[NEDGE + e] : (e - NEDGE);
            int r = atomicAdd(&cnt[dst], 1);
            tmp_rank[e] = (unsigned char)r;   // max degree ~40 << 256
            if (e < NEDGE) local += edge_attr[e];
        }
        #pragma unroll
        for (int s = 1; s < 64; s <<= 1) local += __shfl_xor(local, s, 64);
        if ((threadIdx.x & 63) == 0) atomicAdd(sum_ea, local);
        return;
    }

    // --- xform role: xl = x@W_l + b_l ; xr = x@W_r + b_r via split MFMA ---
    const int tid = threadIdx.x;
    const int n0 = idx * 32;
    for (int it = 0; it < 4; ++it) {
        int idx4 = (it * 256 + tid) * 4;
        int n = idx4 >> 7, j = idx4 & 127;
        int node = n0 + n;
        float4 v = make_float4(0.f, 0.f, 0.f, 0.f);
        if (node < NODES) v = *(const float4*)(x + node * 128 + j);
        *(float4*)&s_x[n][j] = v;
    }
    __syncthreads();

    const int wv4  = tid >> 6;          // wave 0..3
    const int ln   = tid & 63;
    const int lrow = ln & 15;
    const int lk8  = (ln >> 4) << 3;
    const int m    = wv4 >> 1;          // 0: W_l->xl, 1: W_r->xr
    const int cb   = (wv4 & 1) * 64;    // col block within matrix
    const bf16* Bh = m ? wrh : wlh;
    const bf16* Bl = m ? wrl : wll;
    const float* bias = m ? b_r : b_l;

    f32x4 acc[2][4];
    #pragma unroll
    for (int mt = 0; mt < 2; ++mt)
        #pragma unroll
        for (int i = 0; i < 4; ++i)
            acc[mt][i] = (f32x4){0.f, 0.f, 0.f, 0.f};
    #pragma unroll
    for (int kk = 0; kk < 4; ++kk) {
        int k0 = kk * 32 + lk8;
        float a0f[8], a1f[8];
        *(float4*)&a0f[0] = *(const float4*)&s_x[lrow][k0];
        *(float4*)&a0f[4] = *(const float4*)&s_x[lrow][k0 + 4];
        *(float4*)&a1f[0] = *(const float4*)&s_x[16 + lrow][k0];
        *(float4*)&a1f[4] = *(const float4*)&s_x[16 + lrow][k0 + 4];
        bf16x8 a0h, a0l, a1h, a1l;
        split8(a0f, a0h, a0l);
        split8(a1f, a1h, a1l);
        #pragma unroll
        for (int i = 0; i < 4; ++i) {
            int col = cb + (i << 4) + lrow;
            bf16x8 bh = *(const bf16x8*)(Bh + col * 128 + k0);
            bf16x8 bl = *(const bf16x8*)(Bl + col * 128 + k0);
            acc[0][i] = __builtin_amdgcn_mfma_f32_16x16x32_bf16(a0l, bh, acc[0][i], 0, 0, 0);
            acc[0][i] = __builtin_amdgcn_mfma_f32_16x16x32_bf16(a0h, bl, acc[0][i], 0, 0, 0);
            acc[0][i] = __builtin_amdgcn_mfma_f32_16x16x32_bf16(a0h, bh, acc[0][i], 0, 0, 0);
            acc[1][i] = __builtin_amdgcn_mfma_f32_16x16x32_bf16(a1l, bh, acc[1][i], 0, 0, 0);
            acc[1][i] = __builtin_amdgcn_mfma_f32_16x16x32_bf16(a1h, bl, acc[1][i], 0, 0, 0);
            acc[1][i] = __builtin_amdgcn_mfma_f32_16x16x32_bf16(a1h, bh, acc[1][i], 0, 0, 0);
        }
    }
    __syncthreads();                    // all waves done reading s_x
    // restage bf16 results into LDS (reuse s_x memory): [32 rows][264 bf16]
    // cols 0..127 = xl, 136..263 = xr (136 keeps 16B alignment of row+offset)
    bf16* s_o = (bf16*)&s_x[0][0];
    #pragma unroll
    for (int mt = 0; mt < 2; ++mt) {
        #pragma unroll
        for (int i = 0; i < 4; ++i) {
            int colg = cb + (i << 4) + lrow;
            float bv = bias[colg];
            #pragma unroll
            for (int r = 0; r < 4; ++r) {
                int row = (mt << 4) + ((ln >> 4) << 2) + r;
                s_o[row * 264 + m * 136 + colg] = f2bf(acc[mt][i][r] + bv);
            }
        }
    }
    __syncthreads();
    // cooperative coalesced store: 512 chunks of 8 bf16 per matrix
    #pragma unroll
    for (int rep = 0; rep < 2; ++rep) {
        int idx2 = rep * 256 + tid;
        int row = idx2 >> 4, cc = (idx2 & 15) * 8;
        int node = n0 + row;
        if (node < NODES) {
            *(float4*)(xl + node * 128 + cc) = *(const float4*)(s_o + row * 264 + cc);
            *(float4*)(xr + node * 128 + cc) = *(const float4*)(s_o + row * 264 + 136 + cc);
        }
    }
}

// ---------------------------------------------------------------------------
// Multi-block scan. k_scan1: per-block sums of 1024-int chunks -> bsum[b].
// k_scan3: block base by wave-reducing bsum[j<b] in-kernel, then block-local
// exclusive scan -> off[i]; last thread writes off[NODES] = grand total.
// (cursor no longer exists: k_place is atomic-free now.)
// ---------------------------------------------------------------------------
__global__ __launch_bounds__(256) void k_scan1(const int* count, int* bsum) {
    __shared__ int s_w[4];
    const int t = threadIdx.x, b = blockIdx.x;
    const int base = b * SCHUNK + t * 4;
    int s = 0;
    #pragma unroll
    for (int e = 0; e < 4; ++e) {
        int i = base + e;
        if (i < NODES) s += count[i];
    }
    #pragma unroll
    for (int d = 1; d < 64; d <<= 1) s += __shfl_xor(s, d, 64);
    if ((t & 63) == 0) s_w[t >> 6] = s;
    __syncthreads();
    if (t == 0) bsum[b] = s_w[0] + s_w[1] + s_w[2] + s_w[3];
}

__global__ __launch_bounds__(256) void k_scan3(const int* count, const int* bsum,
                                               int* off) {
    __shared__ int s_w[4];
    __shared__ int s_base;
    const int t = threadIdx.x, b = blockIdx.x;
    const int lane = t & 63, wv = t >> 6;
    // block base = sum of bsum[j] for j < b (b <= 48 < 64, one wave does it)
    if (t < 64) {
        int v = (t < b) ? bsum[t] : 0;
        #pragma unroll
        for (int d = 1; d < 64; d <<= 1) v += __shfl_xor(v, d, 64);
        if (t == 0) s_base = v;
    }
    const int base = b * SCHUNK + t * 4;
    int v[4];
    int s = 0;
    #pragma unroll
    for (int e = 0; e < 4; ++e) {
        int i = base + e;
        v[e] = (i < NODES) ? count[i] : 0;
        s += v[e];
    }
    // wave-level inclusive scan of per-thread sums
    int inc = s;
    #pragma unroll
    for (int d = 1; d < 64; d <<= 1) {
        int y = __shfl_up(inc, d, 64);
        if (lane >= d) inc += y;
    }
    if (lane == 63) s_w[wv] = inc;       // wave total
    __syncthreads();
    int woff = 0;
    #pragma unroll
    for (int w = 0; w < 4; ++w) if (w < wv) woff += s_w[w];
    int run = s_base + woff + (inc - s); // exclusive base for this thread
    #pragma unroll
    for (int e = 0; e < 4; ++e) {
        int i = base + e;
        if (i < NODES) {
            off[i] = run; run += v[e];
            if (i == NODES - 1) off[NODES] = run;   // grand total
        }
    }
}

// ---------------------------------------------------------------------------
// k_wconv: transpose FFN weights to [col][k] and split into hi/lo bf16 pairs.
// Runs after k_scan3 (count region dead) into count + old-cursor regions.
// ---------------------------------------------------------------------------
__global__ __launch_bounds__(256) void k_wconv(const float* W1, const float* W2,
                                               bf16* w1h, bf16* w1l,
                                               bf16* w2h, bf16* w2l) {
    int tid = blockIdx.x * blockDim.x + threadIdx.x;   // 65536 threads
    if (tid < 32768) {
        int c = tid >> 7, k = tid & 127;               // w1t[c][k]
        float v = W1[k * 256 + c];
        unsigned short hb = bfbits(v);
        float hv = __uint_as_float((unsigned int)hb << 16);
        w1h[tid] = f2bf(v);
        w1l[tid] = f2bf(v - hv);
    } else {
        int t = tid - 32768;
        int c = t >> 8, k = t & 255;                   // w2t[c][k]
        float v = W2[k * 128 + c];
        unsigned short hb = bfbits(v);
        float hv = __uint_as_float((unsigned int)hb << 16);
        w2h[t] = f2bf(v);
        w2l[t] = f2bf(v - hv);
    }
}

// ---------------------------------------------------------------------------
// k_place (atomic-free): pos = off[dst] + tmp_rank[e]; perm[pos] = (ea|src).
// Ranks are unique within each dst group (assigned by k_fuse's atomics).
// ---------------------------------------------------------------------------
__global__ __launch_bounds__(256) void k_place(const int* ei, const float* edge_attr,
                                               const float* sum_ea, const int* off,
                                               const unsigned char* tmp_rank,
                                               unsigned int* perm) {
    const float meanv = sum_ea[0] * (1.f / (float)NEDGE);
    int tid = blockIdx.x * blockDim.x + threadIdx.x;
    int stride = gridDim.x * blockDim.x;
    for (int e = tid; e < ETOT; e += stride) {
        int src, dst; float eav;
        if (e < NEDGE) { src = ei[e]; dst = ei[NEDGE + e]; eav = edge_attr[e]; }
        else           { src = e - NEDGE; dst = src; eav = meanv; }
        int pos = off[dst] + (int)tmp_rank[e];
        perm[pos] = ((unsigned int)bfbits(eav) << 16) | (unsigned int)src;
    }
}

// ---------------------------------------------------------------------------
// k_agg: [byte-identical to passing R10]
// ---------------------------------------------------------------------------
__global__ __launch_bounds__(256) void k_agg(const unsigned int* xl32,
                                             const unsigned int* xr32,
                                             const unsigned int* perm, const int* off,
                                             const float* W_e, const float* att,
                                             float* outp) {
    const int lane = threadIdx.x & 63;
    const int wave0 = blockIdx.x * 4 + (threadIdx.x >> 6);
    const int nwaves = gridDim.x * 4;
    const int c = 2 * lane;
    const float we1 = W_e[c], we2 = W_e[c + 1];
    const float a1 = att[c], a2 = att[c + 1];
    for (int n = wave0; n < NODES; n += nwaves) {
        unsigned int xru = xr32[n * 64 + lane];
        float xr1 = bflo(xru), xr2 = bfhi(xru);
        int s0 = off[n], s1 = off[n + 1];
        float m = -1e30f, l = 0.f, acc1 = 0.f, acc2 = 0.f;
        int j = s0;
        for (; j + 4 <= s1; j += 4) {
            unsigned int u0 = perm[j];
            unsigned int u1 = perm[j + 1];
            unsigned int u2 = perm[j + 2];
            unsigned int u3 = perm[j + 3];
            unsigned int g0 = xl32[(u0 & 0xffffu) * 64 + lane];
            unsigned int g1 = xl32[(u1 & 0xffffu) * 64 + lane];
            unsigned int g2 = xl32[(u2 & 0xffffu) * 64 + lane];
            unsigned int g3 = xl32[(u3 & 0xffffu) * 64 + lane];
            float e0 = bfhi(u0), e1 = bfhi(u1), e2 = bfhi(u2), e3 = bfhi(u3);
            float x01 = bflo(g0), x02 = bfhi(g0);
            float x11 = bflo(g1), x12 = bfhi(g1);
            float x21 = bflo(g2), x22 = bfhi(g2);
            float x31 = bflo(g3), x32 = bfhi(g3);
            float p0, p1, p2, p3;
            {
                float v1 = x01 + xr1 + e0 * we1, v2 = x02 + xr2 + e0 * we2;
                v1 = (v1 > 0.f) ? v1 : 0.2f * v1;
                v2 = (v2 > 0.f) ? v2 : 0.2f * v2;
                p0 = v1 * a1 + v2 * a2;
            }
            {
                float v1 = x11 + xr1 + e1 * we1, v2 = x12 + xr2 + e1 * we2;
                v1 = (v1 > 0.f) ? v1 : 0.2f * v1;
                v2 = (v2 > 0.f) ? v2 : 0.2f * v2;
                p1 = v1 * a1 + v2 * a2;
            }
            {
                float v1 = x21 + xr1 + e2 * we1, v2 = x22 + xr2 + e2 * we2;
                v1 = (v1 > 0.f) ? v1 : 0.2f * v1;
                v2 = (v2 > 0.f) ? v2 : 0.2f * v2;
                p2 = v1 * a1 + v2 * a2;
            }
            {
                float v1 = x31 + xr1 + e3 * we1, v2 = x32 + xr2 + e3 * we2;
                v1 = (v1 > 0.f) ? v1 : 0.2f * v1;
                v2 = (v2 > 0.f) ? v2 : 0.2f * v2;
                p3 = v1 * a1 + v2 * a2;
            }
            p0 += __shfl_xor(p0, 1, 64); p1 += __shfl_xor(p1, 1, 64);
            p2 += __shfl_xor(p2, 1, 64); p3 += __shfl_xor(p3, 1, 64);
            p0 += __shfl_xor(p0, 2, 64); p1 += __shfl_xor(p1, 2, 64);
            p2 += __shfl_xor(p2, 2, 64); p3 += __shfl_xor(p3, 2, 64);
            p0 += __shfl_xor(p0, 4, 64); p1 += __shfl_xor(p1, 4, 64);
            p2 += __shfl_xor(p2, 4, 64); p3 += __shfl_xor(p3, 4, 64);
            p0 += __shfl_xor(p0, 8, 64); p1 += __shfl_xor(p1, 8, 64);
            p2 += __shfl_xor(p2, 8, 64); p3 += __shfl_xor(p3, 8, 64);
            float nm = fmaxf(fmaxf(m, fmaxf(p0, p1)), fmaxf(p2, p3));
            float sc = __expf(m - nm);
            float E0 = __expf(p0 - nm);
            float E1 = __expf(p1 - nm);
            float E2 = __expf(p2 - nm);
            float E3 = __expf(p3 - nm);
            l = l * sc + E0 + E1 + E2 + E3;
            acc1 = acc1 * sc + E0 * x01 + E1 * x11 + E2 * x21 + E3 * x31;
            acc2 = acc2 * sc + E0 * x02 + E1 * x12 + E2 * x22 + E3 * x32;
            m = nm;
        }
        for (; j < s1; ++j) {
            unsigned int u0 = perm[j];
            unsigned int g0 = xl32[(u0 & 0xffffu) * 64 + lane];
            float e0 = bfhi(u0);
            float x01 = bflo(g0), x02 = bfhi(g0);
            float v1 = x01 + xr1 + e0 * we1, v2 = x02 + xr2 + e0 * we2;
            v1 = (v1 > 0.f) ? v1 : 0.2f * v1;
            v2 = (v2 > 0.f) ? v2 : 0.2f * v2;
            float p = v1 * a1 + v2 * a2;
            p += __shfl_xor(p, 1, 64);
            p += __shfl_xor(p, 2, 64);
            p += __shfl_xor(p, 4, 64);
            p += __shfl_xor(p, 8, 64);
            float nm = fmaxf(m, p);
            float sc = __expf(m - nm);
            float ee = __expf(p - nm);
            l = l * sc + ee;
            acc1 = acc1 * sc + ee * x01;
            acc2 = acc2 * sc + ee * x02;
            m = nm;
        }
        float inv = 1.f / fmaxf(l, 1e-30f);
        *(float2*)(outp + n * 128 + c) = make_float2(acc1 * inv, acc2 * inv);
    }
}

// ---------------------------------------------------------------------------
// k_epi (split-precision MFMA): [byte-identical to passing R2]
// ---------------------------------------------------------------------------
__global__ __launch_bounds__(256) void k_epi(const float* out_agg, const float* x,
                                             const float* bias_out,
                                             const float* W_gate, const float* b_gate,
                                             const bf16* w1h, const bf16* w1l,
                                             const float* b_ffn1,
                                             const bf16* w2h, const bf16* w2l,
                                             const float* b_ffn2,
                                             const float* gamma, const float* beta,
                                             float* out) {
    __shared__ __align__(16) float s_y[32][132];   // h, then y (fp32; residual+LN+FFN1 A)
    __shared__ __align__(16) float s_t[32][260];   // relu(ffn1) fp32 (FFN2 A)
    __shared__ float s_g[32];
    __shared__ float s_mu[32], s_rs[32];
    const int tid = threadIdx.x;
    const int n0 = blockIdx.x * 32;
    int nn = NODES - n0; if (nn > 32) nn = 32;

    // phase 1: h = elu(out_agg + bias_out) -> s_y
    for (int it = 0; it < 4; ++it) {
        int idx4 = (it * 256 + tid) * 4;
        int n = idx4 >> 7, j = idx4 & 127;
        float4 w = make_float4(0.f, 0.f, 0.f, 0.f);
        if (n < nn) {
            float4 v  = *(const float4*)(out_agg + (n0 + n) * 128 + j);
            float4 bv = *(const float4*)(bias_out + j);
            float t0 = v.x + bv.x, t1 = v.y + bv.y;
            float t2 = v.z + bv.z, t3 = v.w + bv.w;
            w.x = (t0 > 0.f) ? t0 : (__expf(t0) - 1.f);
            w.y = (t1 > 0.f) ? t1 : (__expf(t1) - 1.f);
            w.z = (t2 > 0.f) ? t2 : (__expf(t2) - 1.f);
            w.w = (t3 > 0.f) ? t3 : (__expf(t3) - 1.f);
        }
        *(float4*)&s_y[n][j] = w;
    }
    __syncthreads();
    // gate: 8 threads per node, shfl-reduce within 8-lane groups
    {
        int n = tid >> 3, kb = (tid & 7) * 16;
        float g = 0.f;
        #pragma unroll
        for (int k = 0; k < 16; k += 4) {
            float4 w = *(const float4*)(W_gate + kb + k);
            float4 h = *(const float4*)&s_y[n][kb + k];
            g += h.x * w.x + h.y * w.y + h.z * w.z + h.w * w.w;
        }
        g += __shfl_xor(g, 1, 64);
        g += __shfl_xor(g, 2, 64);
        g += __shfl_xor(g, 4, 64);
        if ((tid & 7) == 0) s_g[n] = 1.f / (1.f + __expf(-(g + b_gate[0])));
    }
    __syncthreads();
    // y = g*h + (1-g)*x -> s_y (fp32)
    for (int it = 0; it < 4; ++it) {
        int idx4 = (it * 256 + tid) * 4;
        int n = idx4 >> 7, j = idx4 & 127;
        if (n < nn) {
            float g = s_g[n];
            float4 xv = *(const float4*)(x + (n0 + n) * 128 + j);
            float4 h = *(float4*)&s_y[n][j];
            h.x = g * h.x + (1.f - g) * xv.x;
            h.y = g * h.y + (1.f - g) * xv.y;
            h.z = g * h.z + (1.f - g) * xv.z;
            h.w = g * h.w + (1.f - g) * xv.w;
            *(float4*)&s_y[n][j] = h;
        }
    }
    __syncthreads();

    const int wv   = tid >> 6;          // wave 0..3
    const int ln   = tid & 63;
    const int lrow = ln & 15;           // A row / B,D col within tile
    const int lk8  = (ln >> 4) << 3;    // k chunk base: 0,8,16,24

    // FFN1: t = relu(y @ W1 + b1). M=32 (2 tiles), per-wave N=64 (4 tiles), K=128.
    f32x4 acc1[2][4];
    #pragma unroll
    for (int mt = 0; mt < 2; ++mt)
        #pragma unroll
        for (int i = 0; i < 4; ++i)
            acc1[mt][i] = (f32x4){0.f, 0.f, 0.f, 0.f};
    #pragma unroll
    for (int kk = 0; kk < 4; ++kk) {
        int k0 = kk * 32 + lk8;
        float a0f[8], a1f[8];
        *(float4*)&a0f[0] = *(const float4*)&s_y[lrow][k0];
        *(float4*)&a0f[4] = *(const float4*)&s_y[lrow][k0 + 4];
        *(float4*)&a1f[0] = *(const float4*)&s_y[16 + lrow][k0];
        *(float4*)&a1f[4] = *(const float4*)&s_y[16 + lrow][k0 + 4];
        bf16x8 a0h, a0l, a1h, a1l;
        split8(a0f, a0h, a0l);
        split8(a1f, a1h, a1l);
        #pragma unroll
        for (int i = 0; i < 4; ++i) {
            int col = (wv << 6) + (i << 4) + lrow;
            bf16x8 bh = *(const bf16x8*)(w1h + col * 128 + k0);
            bf16x8 bl = *(const bf16x8*)(w1l + col * 128 + k0);
            acc1[0][i] = __builtin_amdgcn_mfma_f32_16x16x32_bf16(a0l, bh, acc1[0][i], 0, 0, 0);
            acc1[0][i] = __builtin_amdgcn_mfma_f32_16x16x32_bf16(a0h, bl, acc1[0][i], 0, 0, 0);
            acc1[0][i] = __builtin_amdgcn_mfma_f32_16x16x32_bf16(a0h, bh, acc1[0][i], 0, 0, 0);
            acc1[1][i] = __builtin_amdgcn_mfma_f32_16x16x32_bf16(a1l, bh, acc1[1][i], 0, 0, 0);
            acc1[1][i] = __builtin_amdgcn_mfma_f32_16x16x32_bf16(a1h, bl, acc1[1][i], 0, 0, 0);
            acc1[1][i] = __builtin_amdgcn_mfma_f32_16x16x32_bf16(a1h, bh, acc1[1][i], 0, 0, 0);
        }
    }
    // epilogue: +b1, relu -> s_t (fp32; lanes 0-15 write consecutive cols)
    #pragma unroll
    for (int mt = 0; mt < 2; ++mt) {
        #pragma unroll
        for (int i = 0; i < 4; ++i) {
            int col = (wv << 6) + (i << 4) + lrow;
            float bv = b_ffn1[col];
            #pragma unroll
            for (int r = 0; r < 4; ++r) {
                int row = (mt << 4) + ((ln >> 4) << 2) + r;
                s_t[row][col] = fmaxf(acc1[mt][i][r] + bv, 0.f);
            }
        }
    }
    __syncthreads();

    // FFN2: ffn = t @ W2 + b2. M=32 (2 tiles), per-wave N=32 (2 tiles), K=256.
    f32x4 acc2[2][2];
    #pragma unroll
    for (int mt = 0; mt < 2; ++mt)
        #pragma unroll
        for (int c = 0; c < 2; ++c)
            acc2[mt][c] = (f32x4){0.f, 0.f, 0.f, 0.f};
    #pragma unroll
    for (int kk = 0; kk < 8; ++kk) {
        int k0 = kk * 32 + lk8;
        float a0f[8], a1f[8];
        *(float4*)&a0f[0] = *(const float4*)&s_t[lrow][k0];
        *(float4*)&a0f[4] = *(const float4*)&s_t[lrow][k0 + 4];
        *(float4*)&a1f[0] = *(const float4*)&s_t[16 + lrow][k0];
        *(float4*)&a1f[4] = *(const float4*)&s_t[16 + lrow][k0 + 4];
        bf16x8 a0h, a0l, a1h, a1l;
        split8(a0f, a0h, a0l);
        split8(a1f, a1h, a1l);
        #pragma unroll
        for (int c = 0; c < 2; ++c) {
            int col = (wv << 5) + (c << 4) + lrow;
            bf16x8 bh = *(const bf16x8*)(w2h + col * 256 + k0);
            bf16x8 bl = *(const bf16x8*)(w2l + col * 256 + k0);
            acc2[0][c] = __builtin_amdgcn_mfma_f32_16x16x32_bf16(a0l, bh, acc2[0][c], 0, 0, 0);
            acc2[0][c] = __builtin_amdgcn_mfma_f32_16x16x32_bf16(a0h, bl, acc2[0][c], 0, 0, 0);
            acc2[0][c] = __builtin_amdgcn_mfma_f32_16x16x32_bf16(a0h, bh, acc2[0][c], 0, 0, 0);
            acc2[1][c] = __builtin_amdgcn_mfma_f32_16x16x32_bf16(a1l, bh, acc2[1][c], 0, 0, 0);
            acc2[1][c] = __builtin_amdgcn_mfma_f32_16x16x32_bf16(a1h, bl, acc2[1][c], 0, 0, 0);
            acc2[1][c] = __builtin_amdgcn_mfma_f32_16x16x32_bf16(a1h, bh, acc2[1][c], 0, 0, 0);
        }
    }
    // epilogue: y += ffn + b2  (disjoint (row,col) per lane across block)
    #pragma unroll
    for (int mt = 0; mt < 2; ++mt) {
        #pragma unroll
        for (int c = 0; c < 2; ++c) {
            int col = (wv << 5) + (c << 4) + lrow;
            float bv = b_ffn2[col];
            #pragma unroll
            for (int r = 0; r < 4; ++r) {
                int row = (mt << 4) + ((ln >> 4) << 2) + r;
                s_y[row][col] += acc2[mt][c][r] + bv;
            }
        }
    }
    __syncthreads();
    // LayerNorm stats: 8 threads per node
    {
        int n = tid >> 3, kb = (tid & 7) * 16;
        float s = 0.f, ss = 0.f;
        #pragma unroll
        for (int k = 0; k < 16; k += 4) {
            float4 v = *(const float4*)&s_y[n][kb + k];
            s  += v.x + v.y + v.z + v.w;
            ss += v.x * v.x + v.y * v.y + v.z * v.z + v.w * v.w;
        }
        s  += __shfl_xor(s, 1, 64);  ss += __shfl_xor(ss, 1, 64);
        s  += __shfl_xor(s, 2, 64);  ss += __shfl_xor(ss, 2, 64);
        s  += __shfl_xor(s, 4, 64);  ss += __shfl_xor(ss, 4, 64);
        if ((tid & 7) == 0) {
            float mu = s * (1.f / 128.f);
            float var = ss * (1.f / 128.f) - mu * mu;
            s_mu[n] = mu;
            s_rs[n] = rsqrtf(fmaxf(var, 0.f) + 1e-5f);
        }
    }
    __syncthreads();
    // normalize + store (fp32)
    for (int it = 0; it < 4; ++it) {
        int idx4 = (it * 256 + tid) * 4;
        int n = idx4 >> 7, j = idx4 & 127;
        if (n < nn) {
            float mu = s_mu[n], rs = s_rs[n];
            float4 gv = *(const float4*)(gamma + j);
            float4 bv = *(const float4*)(beta + j);
            float4 v = *(const float4*)&s_y[n][j];
            float4 o;
            o.x = (v.x - mu) * rs * gv.x + bv.x;
            o.y = (v.y - mu) * rs * gv.y + bv.y;
            o.z = (v.z - mu) * rs * gv.z + bv.z;
            o.w = (v.w - mu) * rs * gv.w + bv.w;
            *(float4*)(out + (n0 + n) * 128 + j) = o;
        }
    }
}

// ---------------------------------------------------------------------------
extern "C" void kernel_launch(void* const* d_in, const int* in_sizes, int n_in,
                              void* d_out, int out_size, void* d_ws, size_t ws_size,
                              hipStream_t stream) {
    const float* x         = (const float*)d_in[0];
    const float* edge_attr = (const float*)d_in[1];
    const int* edge_index  = (const int*)d_in[17];
    float* out = (float*)d_out;

    char* base = (char*)d_ws;
    // workspace layout: EXACTLY the hardware-proven layout (29,600,064 B).
    float* sum_ea  = (float*)(base + 16);                     // 16
    int*   cnt     = (int*)  (base + 32);                     // 200000 (counts)
    int*   off     = (int*)  (base + 200032);                 // 200004 (+pad)
    /* old cursor region (base+400064, 200000 B): now only holds w2 pair */
    unsigned int* perm = (unsigned int*)(base + 600064);      // 3400000
    bf16*  xl      = (bf16*) (base + 4000064);                // 12800000
    bf16*  xr      = (bf16*) (base + 16800064);               // 12800000
    // scan block sums: head of perm region (dead until k_place). 49 ints.
    int*   bsum    = (int*)  (base + 600064);
    // xform weight split pairs: perm region +1024 (dead until k_place;
    // consumed by k_fuse which precedes it). 4 x 32768 B.
    bf16*  wxlh    = (bf16*) (base + 600064 + 1024);
    bf16*  wxll    = (bf16*) (base + 600064 + 1024 + 32768);
    bf16*  wxrh    = (bf16*) (base + 600064 + 1024 + 65536);
    bf16*  wxrl    = (bf16*) (base + 600064 + 1024 + 98304);
    // FFN weight split pairs (as before):
    bf16*  w1t_hi  = (bf16*) (base + 32);                     // cnt region, dead after scan3
    bf16*  w1t_lo  = (bf16*) (base + 32 + 65536);
    bf16*  w2t_hi  = (bf16*) (base + 400064);                 // old cursor region
    bf16*  w2t_lo  = (bf16*) (base + 400064 + 65536);
    // per-edge rank temp: head of d_out (dead until k_agg overwrites out).
    unsigned char* tmp_rank = (unsigned char*)d_out;          // 850000 B

    hipMemsetAsync(sum_ea, 0, 16, stream);
    hipMemsetAsync(cnt, 0, NODES * sizeof(int), stream);

    const int NTILES = (NODES + 31) / 32;  // 1563

    k_wxf   <<<128, 256, 0, stream>>>((const float*)d_in[2], (const float*)d_in[4],
                                      wxlh, wxll, wxrh, wxrl);
    k_fuse  <<<FUSE_GRID, 256, 0, stream>>>(edge_attr, edge_index, sum_ea, cnt,
                                            tmp_rank, x,
                                            wxlh, wxll, wxrh, wxrl,
                                            (const float*)d_in[3], (const float*)d_in[5],
                                            xl, xr);
    k_scan1 <<<SBLK, 256, 0, stream>>>(cnt, bsum);
    k_scan3 <<<SBLK, 256, 0, stream>>>(cnt, bsum, off);
    k_place <<<1024, 256, 0, stream>>>(edge_index, edge_attr, sum_ea, off,
                                       tmp_rank, perm);
    k_wconv <<<256, 256, 0, stream>>>((const float*)d_in[11], (const float*)d_in[13],
                                      w1t_hi, w1t_lo, w2t_hi, w2t_lo);
    k_agg   <<<3125, 256, 0, stream>>>((const unsigned int*)xl,
                                       (const unsigned int*)xr,
                                       perm, off,
                                       (const float*)d_in[6], (const float*)d_in[7],
                                       out);
    k_epi   <<<NTILES, 256, 0, stream>>>(out, x, (const float*)d_in[8],
                                         (const float*)d_in[9], (const float*)d_in[10],
                                         w1t_hi, w1t_lo, (const float*)d_in[12],
                                         w2t_hi, w2t_lo, (const float*)d_in[14],
                                         (const float*)d_in[15], (const float*)d_in[16],
                                         out);
}

// Round 7
// 349.748 us; speedup vs baseline: 1.6109x; 1.0021x over previous
//
#include <hip/hip_runtime.h>
#include <hip/hip_bf16.h>

#define NODES 50000
#define NEDGE 800000
#define ETOT  850000   /* NEDGE + NODES self loops */

#define NRANGE 49            /* ceil(NODES/1024) dst ranges */
#define SB 256               /* scatter/hist blocks */
#define ES ((ETOT + SB - 1) / SB)   /* 3321 edges per slice */

#define XF_TILES 1563        /* ceil(NODES/32) */
#define HIST_BLKS 256
#define FUSE_GRID (2 * HIST_BLKS + (XF_TILES - HIST_BLKS))  /* 1819 */

typedef __hip_bfloat16 bf16;
typedef __attribute__((ext_vector_type(8))) short bf16x8;
typedef __attribute__((ext_vector_type(4))) float f32x4;

__device__ __forceinline__ bf16 f2bf(float v) { return __float2bfloat16(v); }
__device__ __forceinline__ float bflo(unsigned int v) { return __uint_as_float(v << 16); }
__device__ __forceinline__ float bfhi(unsigned int v) { return __uint_as_float(v & 0xffff0000u); }

__device__ __forceinline__ unsigned int pack2(float a, float b) {
    bf16 x = f2bf(a), y = f2bf(b);
    unsigned short xs = *reinterpret_cast<unsigned short*>(&x);
    unsigned short ys = *reinterpret_cast<unsigned short*>(&y);
    return ((unsigned int)ys << 16) | (unsigned int)xs;
}

__device__ __forceinline__ unsigned short bfbits(float v) {
    bf16 x = f2bf(v);
    return *reinterpret_cast<unsigned short*>(&x);
}

// split 8 fp32 -> hi/lo bf16x8 (Dekker split: lo = v - float(hi), exact)
__device__ __forceinline__ void split8(const float* v, bf16x8& hi, bf16x8& lo) {
    #pragma unroll
    for (int e = 0; e < 8; ++e) {
        unsigned short hb = bfbits(v[e]);
        float hv = __uint_as_float((unsigned int)hb << 16);
        unsigned short lb = bfbits(v[e] - hv);
        ((short*)&hi)[e] = (short)hb;
        ((short*)&lo)[e] = (short)lb;
    }
}

// ---------------------------------------------------------------------------
// k_wxf: W_l/W_r [128k x 128c] -> transposed [c][k] hi/lo bf16 split pairs.
// Outputs in perm region (+1024): consumed by k_fuse, dead before k_group
// writes perm.
// ---------------------------------------------------------------------------
__global__ __launch_bounds__(256) void k_wxf(const float* W_l, const float* W_r,
                                             bf16* wlh, bf16* wll,
                                             bf16* wrh, bf16* wrl) {
    int tid = blockIdx.x * blockDim.x + threadIdx.x;   // 32768 threads
    int m = tid >> 14;
    int t = tid & 16383;
    int c = t >> 7, k = t & 127;
    const float* W = m ? W_r : W_l;
    float v = W[k * 128 + c];
    unsigned short hb = bfbits(v);
    float hv = __uint_as_float((unsigned int)hb << 16);
    bf16* dh = m ? wrh : wlh;
    bf16* dl = m ? wrl : wll;
    dh[t] = f2bf(v);
    dl[t] = f2bf(v - hv);
}

// ---------------------------------------------------------------------------
// k_fuse: grid-partitioned fusion of range-histogram (LDS atomics only, no
// device atomics) with MFMA xform. hist role: slice of edges -> 49-range
// LDS histogram -> rhist[blk][64]; plus edge_attr sum (4 global atomics/blk).
// ---------------------------------------------------------------------------
__global__ __launch_bounds__(256) void k_fuse(const float* edge_attr, const int* ei,
                                              float* sum_ea, int* rhist,
                                              const float* x,
                                              const bf16* wlh, const bf16* wll,
                                              const bf16* wrh, const bf16* wrl,
                                              const float* b_l, const float* b_r,
                                              bf16* xl, bf16* xr) {
    __shared__ __align__(16) float s_x[32][132];
    const int bid = blockIdx.x;
    int idx;
    bool isprep;
    if (bid < 2 * HIST_BLKS) { isprep = (bid & 1); idx = bid >> 1; }
    else { isprep = false; idx = HIST_BLKS + (bid - 2 * HIST_BLKS); }

    if (isprep) {
        // --- hist role (block-uniform branch) ---
        int* hcnt = (int*)&s_x[0][0];
        const int t = threadIdx.x;
        if (t < 64) hcnt[t] = 0;
        __syncthreads();
        const int e0 = idx * ES;
        int e1 = e0 + ES; if (e1 > ETOT) e1 = ETOT;
        float local = 0.f;
        for (int e = e0 + t; e < e1; e += 256) {
            int dst = (e < NEDGE) ? ei[NEDGE + e] : (e - NEDGE);
            atomicAdd(&hcnt[dst >> 10], 1);
            if (e < NEDGE) local += edge_attr[e];
        }
        #pragma unroll
        for (int s = 1; s < 64; s <<= 1) local += __shfl_xor(local, s, 64);
        if ((t & 63) == 0) atomicAdd(sum_ea, local);
        __syncthreads();
        if (t < 64) rhist[idx * 64 + t] = hcnt[t];
        return;
    }

    // --- xform role: xl = x@W_l + b_l ; xr = x@W_r + b_r via split MFMA ---
    const int tid = threadIdx.x;
    const int n0 = idx * 32;
    for (int it = 0; it < 4; ++it) {
        int idx4 = (it * 256 + tid) * 4;
        int n = idx4 >> 7, j = idx4 & 127;
        int node = n0 + n;
        float4 v = make_float4(0.f, 0.f, 0.f, 0.f);
        if (node < NODES) v = *(const float4*)(x + node * 128 + j);
        *(float4*)&s_x[n][j] = v;
    }
    __syncthreads();

    const int wv4  = tid >> 6;          // wave 0..3
    const int ln   = tid & 63;
    const int lrow = ln & 15;
    const int lk8  = (ln >> 4) << 3;
    const int m    = wv4 >> 1;          // 0: W_l->xl, 1: W_r->xr
    const int cb   = (wv4 & 1) * 64;    // col block within matrix
    const bf16* Bh = m ? wrh : wlh;
    const bf16* Bl = m ? wrl : wll;
    const float* bias = m ? b_r : b_l;

    f32x4 acc[2][4];
    #pragma unroll
    for (int mt = 0; mt < 2; ++mt)
        #pragma unroll
        for (int i = 0; i < 4; ++i)
            acc[mt][i] = (f32x4){0.f, 0.f, 0.f, 0.f};
    #pragma unroll
    for (int kk = 0; kk < 4; ++kk) {
        int k0 = kk * 32 + lk8;
        float a0f[8], a1f[8];
        *(float4*)&a0f[0] = *(const float4*)&s_x[lrow][k0];
        *(float4*)&a0f[4] = *(const float4*)&s_x[lrow][k0 + 4];
        *(float4*)&a1f[0] = *(const float4*)&s_x[16 + lrow][k0];
        *(float4*)&a1f[4] = *(const float4*)&s_x[16 + lrow][k0 + 4];
        bf16x8 a0h, a0l, a1h, a1l;
        split8(a0f, a0h, a0l);
        split8(a1f, a1h, a1l);
        #pragma unroll
        for (int i = 0; i < 4; ++i) {
            int col = cb + (i << 4) + lrow;
            bf16x8 bh = *(const bf16x8*)(Bh + col * 128 + k0);
            bf16x8 bl = *(const bf16x8*)(Bl + col * 128 + k0);
            acc[0][i] = __builtin_amdgcn_mfma_f32_16x16x32_bf16(a0l, bh, acc[0][i], 0, 0, 0);
            acc[0][i] = __builtin_amdgcn_mfma_f32_16x16x32_bf16(a0h, bl, acc[0][i], 0, 0, 0);
            acc[0][i] = __builtin_amdgcn_mfma_f32_16x16x32_bf16(a0h, bh, acc[0][i], 0, 0, 0);
            acc[1][i] = __builtin_amdgcn_mfma_f32_16x16x32_bf16(a1l, bh, acc[1][i], 0, 0, 0);
            acc[1][i] = __builtin_amdgcn_mfma_f32_16x16x32_bf16(a1h, bl, acc[1][i], 0, 0, 0);
            acc[1][i] = __builtin_amdgcn_mfma_f32_16x16x32_bf16(a1h, bh, acc[1][i], 0, 0, 0);
        }
    }
    __syncthreads();                    // all waves done reading s_x
    // restage bf16 results into LDS (reuse s_x memory): [32 rows][264 bf16]
    bf16* s_o = (bf16*)&s_x[0][0];
    #pragma unroll
    for (int mt = 0; mt < 2; ++mt) {
        #pragma unroll
        for (int i = 0; i < 4; ++i) {
            int colg = cb + (i << 4) + lrow;
            float bv = bias[colg];
            #pragma unroll
            for (int r = 0; r < 4; ++r) {
                int row = (mt << 4) + ((ln >> 4) << 2) + r;
                s_o[row * 264 + m * 136 + colg] = f2bf(acc[mt][i][r] + bv);
            }
        }
    }
    __syncthreads();
    // cooperative coalesced store
    #pragma unroll
    for (int rep = 0; rep < 2; ++rep) {
        int idx2 = rep * 256 + tid;
        int row = idx2 >> 4, cc = (idx2 & 15) * 8;
        int node = n0 + row;
        if (node < NODES) {
            *(float4*)(xl + node * 128 + cc) = *(const float4*)(s_o + row * 264 + cc);
            *(float4*)(xr + node * 128 + cc) = *(const float4*)(s_o + row * 264 + 136 + cc);
        }
    }
}

// ---------------------------------------------------------------------------
// k_rscan (1 block, 256 thr): in-place scan of rhist[256][64] ->
// per-(block,range) absolute cursors; base_r[r] = perm start of range r.
// ---------------------------------------------------------------------------
__global__ __launch_bounds__(256) void k_rscan(int* rhist, int* base_r, int* off) {
    __shared__ int s_w[4];
    __shared__ int s_run;
    const int t = threadIdx.x, lane = t & 63, w = t >> 6;
    if (t == 0) s_run = 0;
    __syncthreads();
    for (int r = 0; r < NRANGE; ++r) {
        int v = rhist[t * 64 + r];
        int inc = v;
        #pragma unroll
        for (int d = 1; d < 64; d <<= 1) {
            int y = __shfl_up(inc, d, 64);
            if (lane >= d) inc += y;
        }
        if (lane == 63) s_w[w] = inc;
        __syncthreads();
        int woff = 0;
        #pragma unroll
        for (int ww = 0; ww < 4; ++ww) if (ww < w) woff += s_w[ww];
        int tot = s_w[0] + s_w[1] + s_w[2] + s_w[3];
        int runv = s_run;
        rhist[t * 64 + r] = runv + woff + (inc - v);
        if (t == 0) base_r[r] = runv;
        __syncthreads();
        if (t == 0) s_run = runv + tot;
        __syncthreads();
    }
    if (t == 0) { base_r[NRANGE] = ETOT; off[NODES] = ETOT; }
}

// ---------------------------------------------------------------------------
// k_scatter (256 blocks): partition all edges by dst-range into tmp2 using
// per-block LDS cursors (no device atomics). tmp2[pos] = {dst, ea|src}.
// ---------------------------------------------------------------------------
__global__ __launch_bounds__(256) void k_scatter(const int* ei, const float* edge_attr,
                                                 const float* sum_ea, const int* rhist,
                                                 uint2* tmp2) {
    __shared__ int cur[64];
    const int b = blockIdx.x, t = threadIdx.x;
    if (t < 64) cur[t] = rhist[b * 64 + t];
    __syncthreads();
    const float meanv = sum_ea[0] * (1.f / (float)NEDGE);
    const int e0 = b * ES;
    int e1 = e0 + ES; if (e1 > ETOT) e1 = ETOT;
    for (int e = e0 + t; e < e1; e += 256) {
        int src, dst; float eav;
        if (e < NEDGE) { src = ei[e]; dst = ei[NEDGE + e]; eav = edge_attr[e]; }
        else           { src = e - NEDGE; dst = src; eav = meanv; }
        int pos = atomicAdd(&cur[dst >> 10], 1);
        tmp2[pos] = make_uint2((unsigned int)dst,
                               ((unsigned int)bfbits(eav) << 16) | (unsigned int)src);
    }
}

// ---------------------------------------------------------------------------
// k_group (49 blocks x 1024): per-range local count (LDS) -> block scan ->
// off[] write + rank-scatter into perm. No device atomics.
// ---------------------------------------------------------------------------
__global__ __launch_bounds__(1024) void k_group(const uint2* tmp2, const int* base_r,
                                                int* off, unsigned int* perm) {
    __shared__ int lcnt[1024];
    __shared__ int s_w16[16];
    const int r = blockIdx.x, t = threadIdx.x;
    const int lane = t & 63, w = t >> 6;
    const int n0 = r << 10;
    const int s0 = base_r[r], s1 = base_r[r + 1];
    lcnt[t] = 0;
    __syncthreads();
    for (int i = s0 + t; i < s1; i += 1024) {
        int d = (int)tmp2[i].x;
        atomicAdd(&lcnt[d - n0], 1);
    }
    __syncthreads();
    int v = lcnt[t];
    int inc = v;
    #pragma unroll
    for (int d = 1; d < 64; d <<= 1) {
        int y = __shfl_up(inc, d, 64);
        if (lane >= d) inc += y;
    }
    if (lane == 63) s_w16[w] = inc;
    __syncthreads();                      // also guarantees all lcnt reads done
    int woff = 0;
    #pragma unroll
    for (int ww = 0; ww < 16; ++ww) if (ww < w) woff += s_w16[ww];
    int pos0 = s0 + woff + (inc - v);     // absolute start for dst n0+t
    lcnt[t] = pos0;
    if (n0 + t < NODES) off[n0 + t] = pos0;
    __syncthreads();
    for (int i = s0 + t; i < s1; i += 1024) {
        uint2 p = tmp2[i];
        int pos = atomicAdd(&lcnt[(int)p.x - n0], 1);
        perm[pos] = p.y;
    }
}

// ---------------------------------------------------------------------------
// k_wconv: transpose FFN weights to [col][k], hi/lo bf16 split pairs.
// Runs after k_group (rhist and base_r regions dead by then).
// ---------------------------------------------------------------------------
__global__ __launch_bounds__(256) void k_wconv(const float* W1, const float* W2,
                                               bf16* w1h, bf16* w1l,
                                               bf16* w2h, bf16* w2l) {
    int tid = blockIdx.x * blockDim.x + threadIdx.x;   // 65536 threads
    if (tid < 32768) {
        int c = tid >> 7, k = tid & 127;               // w1t[c][k]
        float v = W1[k * 256 + c];
        unsigned short hb = bfbits(v);
        float hv = __uint_as_float((unsigned int)hb << 16);
        w1h[tid] = f2bf(v);
        w1l[tid] = f2bf(v - hv);
    } else {
        int t = tid - 32768;
        int c = t >> 8, k = t & 255;                   // w2t[c][k]
        float v = W2[k * 128 + c];
        unsigned short hb = bfbits(v);
        float hv = __uint_as_float((unsigned int)hb << 16);
        w2h[t] = f2bf(v);
        w2l[t] = f2bf(v - hv);
    }
}

// ---------------------------------------------------------------------------
// k_agg: [byte-identical to passing R10]
// ---------------------------------------------------------------------------
__global__ __launch_bounds__(256) void k_agg(const unsigned int* xl32,
                                             const unsigned int* xr32,
                                             const unsigned int* perm, const int* off,
                                             const float* W_e, const float* att,
                                             float* outp) {
    const int lane = threadIdx.x & 63;
    const int wave0 = blockIdx.x * 4 + (threadIdx.x >> 6);
    const int nwaves = gridDim.x * 4;
    const int c = 2 * lane;
    const float we1 = W_e[c], we2 = W_e[c + 1];
    const float a1 = att[c], a2 = att[c + 1];
    for (int n = wave0; n < NODES; n += nwaves) {
        unsigned int xru = xr32[n * 64 + lane];
        float xr1 = bflo(xru), xr2 = bfhi(xru);
        int s0 = off[n], s1 = off[n + 1];
        float m = -1e30f, l = 0.f, acc1 = 0.f, acc2 = 0.f;
        int j = s0;
        for (; j + 4 <= s1; j += 4) {
            unsigned int u0 = perm[j];
            unsigned int u1 = perm[j + 1];
            unsigned int u2 = perm[j + 2];
            unsigned int u3 = perm[j + 3];
            unsigned int g0 = xl32[(u0 & 0xffffu) * 64 + lane];
            unsigned int g1 = xl32[(u1 & 0xffffu) * 64 + lane];
            unsigned int g2 = xl32[(u2 & 0xffffu) * 64 + lane];
            unsigned int g3 = xl32[(u3 & 0xffffu) * 64 + lane];
            float e0 = bfhi(u0), e1 = bfhi(u1), e2 = bfhi(u2), e3 = bfhi(u3);
            float x01 = bflo(g0), x02 = bfhi(g0);
            float x11 = bflo(g1), x12 = bfhi(g1);
            float x21 = bflo(g2), x22 = bfhi(g2);
            float x31 = bflo(g3), x32 = bfhi(g3);
            float p0, p1, p2, p3;
            {
                float v1 = x01 + xr1 + e0 * we1, v2 = x02 + xr2 + e0 * we2;
                v1 = (v1 > 0.f) ? v1 : 0.2f * v1;
                v2 = (v2 > 0.f) ? v2 : 0.2f * v2;
                p0 = v1 * a1 + v2 * a2;
            }
            {
                float v1 = x11 + xr1 + e1 * we1, v2 = x12 + xr2 + e1 * we2;
                v1 = (v1 > 0.f) ? v1 : 0.2f * v1;
                v2 = (v2 > 0.f) ? v2 : 0.2f * v2;
                p1 = v1 * a1 + v2 * a2;
            }
            {
                float v1 = x21 + xr1 + e2 * we1, v2 = x22 + xr2 + e2 * we2;
                v1 = (v1 > 0.f) ? v1 : 0.2f * v1;
                v2 = (v2 > 0.f) ? v2 : 0.2f * v2;
                p2 = v1 * a1 + v2 * a2;
            }
            {
                float v1 = x31 + xr1 + e3 * we1, v2 = x32 + xr2 + e3 * we2;
                v1 = (v1 > 0.f) ? v1 : 0.2f * v1;
                v2 = (v2 > 0.f) ? v2 : 0.2f * v2;
                p3 = v1 * a1 + v2 * a2;
            }
            p0 += __shfl_xor(p0, 1, 64); p1 += __shfl_xor(p1, 1, 64);
            p2 += __shfl_xor(p2, 1, 64); p3 += __shfl_xor(p3, 1, 64);
            p0 += __shfl_xor(p0, 2, 64); p1 += __shfl_xor(p1, 2, 64);
            p2 += __shfl_xor(p2, 2, 64); p3 += __shfl_xor(p3, 2, 64);
            p0 += __shfl_xor(p0, 4, 64); p1 += __shfl_xor(p1, 4, 64);
            p2 += __shfl_xor(p2, 4, 64); p3 += __shfl_xor(p3, 4, 64);
            p0 += __shfl_xor(p0, 8, 64); p1 += __shfl_xor(p1, 8, 64);
            p2 += __shfl_xor(p2, 8, 64); p3 += __shfl_xor(p3, 8, 64);
            float nm = fmaxf(fmaxf(m, fmaxf(p0, p1)), fmaxf(p2, p3));
            float sc = __expf(m - nm);
            float E0 = __expf(p0 - nm);
            float E1 = __expf(p1 - nm);
            float E2 = __expf(p2 - nm);
            float E3 = __expf(p3 - nm);
            l = l * sc + E0 + E1 + E2 + E3;
            acc1 = acc1 * sc + E0 * x01 + E1 * x11 + E2 * x21 + E3 * x31;
            acc2 = acc2 * sc + E0 * x02 + E1 * x12 + E2 * x22 + E3 * x32;
            m = nm;
        }
        for (; j < s1; ++j) {
            unsigned int u0 = perm[j];
            unsigned int g0 = xl32[(u0 & 0xffffu) * 64 + lane];
            float e0 = bfhi(u0);
            float x01 = bflo(g0), x02 = bfhi(g0);
            float v1 = x01 + xr1 + e0 * we1, v2 = x02 + xr2 + e0 * we2;
            v1 = (v1 > 0.f) ? v1 : 0.2f * v1;
            v2 = (v2 > 0.f) ? v2 : 0.2f * v2;
            float p = v1 * a1 + v2 * a2;
            p += __shfl_xor(p, 1, 64);
            p += __shfl_xor(p, 2, 64);
            p += __shfl_xor(p, 4, 64);
            p += __shfl_xor(p, 8, 64);
            float nm = fmaxf(m, p);
            float sc = __expf(m - nm);
            float ee = __expf(p - nm);
            l = l * sc + ee;
            acc1 = acc1 * sc + ee * x01;
            acc2 = acc2 * sc + ee * x02;
            m = nm;
        }
        float inv = 1.f / fmaxf(l, 1e-30f);
        *(float2*)(outp + n * 128 + c) = make_float2(acc1 * inv, acc2 * inv);
    }
}

// ---------------------------------------------------------------------------
// k_epi (split-precision MFMA): [byte-identical to passing R2]
// ---------------------------------------------------------------------------
__global__ __launch_bounds__(256) void k_epi(const float* out_agg, const float* x,
                                             const float* bias_out,
                                             const float* W_gate, const float* b_gate,
                                             const bf16* w1h, const bf16* w1l,
                                             const float* b_ffn1,
                                             const bf16* w2h, const bf16* w2l,
                                             const float* b_ffn2,
                                             const float* gamma, const float* beta,
                                             float* out) {
    __shared__ __align__(16) float s_y[32][132];   // h, then y (fp32; residual+LN+FFN1 A)
    __shared__ __align__(16) float s_t[32][260];   // relu(ffn1) fp32 (FFN2 A)
    __shared__ float s_g[32];
    __shared__ float s_mu[32], s_rs[32];
    const int tid = threadIdx.x;
    const int n0 = blockIdx.x * 32;
    int nn = NODES - n0; if (nn > 32) nn = 32;

    // phase 1: h = elu(out_agg + bias_out) -> s_y
    for (int it = 0; it < 4; ++it) {
        int idx4 = (it * 256 + tid) * 4;
        int n = idx4 >> 7, j = idx4 & 127;
        float4 w = make_float4(0.f, 0.f, 0.f, 0.f);
        if (n < nn) {
            float4 v  = *(const float4*)(out_agg + (n0 + n) * 128 + j);
            float4 bv = *(const float4*)(bias_out + j);
            float t0 = v.x + bv.x, t1 = v.y + bv.y;
            float t2 = v.z + bv.z, t3 = v.w + bv.w;
            w.x = (t0 > 0.f) ? t0 : (__expf(t0) - 1.f);
            w.y = (t1 > 0.f) ? t1 : (__expf(t1) - 1.f);
            w.z = (t2 > 0.f) ? t2 : (__expf(t2) - 1.f);
            w.w = (t3 > 0.f) ? t3 : (__expf(t3) - 1.f);
        }
        *(float4*)&s_y[n][j] = w;
    }
    __syncthreads();
    // gate: 8 threads per node, shfl-reduce within 8-lane groups
    {
        int n = tid >> 3, kb = (tid & 7) * 16;
        float g = 0.f;
        #pragma unroll
        for (int k = 0; k < 16; k += 4) {
            float4 w = *(const float4*)(W_gate + kb + k);
            float4 h = *(const float4*)&s_y[n][kb + k];
            g += h.x * w.x + h.y * w.y + h.z * w.z + h.w * w.w;
        }
        g += __shfl_xor(g, 1, 64);
        g += __shfl_xor(g, 2, 64);
        g += __shfl_xor(g, 4, 64);
        if ((tid & 7) == 0) s_g[n] = 1.f / (1.f + __expf(-(g + b_gate[0])));
    }
    __syncthreads();
    // y = g*h + (1-g)*x -> s_y (fp32)
    for (int it = 0; it < 4; ++it) {
        int idx4 = (it * 256 + tid) * 4;
        int n = idx4 >> 7, j = idx4 & 127;
        if (n < nn) {
            float g = s_g[n];
            float4 xv = *(const float4*)(x + (n0 + n) * 128 + j);
            float4 h = *(float4*)&s_y[n][j];
            h.x = g * h.x + (1.f - g) * xv.x;
            h.y = g * h.y + (1.f - g) * xv.y;
            h.z = g * h.z + (1.f - g) * xv.z;
            h.w = g * h.w + (1.f - g) * xv.w;
            *(float4*)&s_y[n][j] = h;
        }
    }
    __syncthreads();

    const int wv   = tid >> 6;          // wave 0..3
    const int ln   = tid & 63;
    const int lrow = ln & 15;           // A row / B,D col within tile
    const int lk8  = (ln >> 4) << 3;    // k chunk base: 0,8,16,24

    // FFN1: t = relu(y @ W1 + b1). M=32 (2 tiles), per-wave N=64 (4 tiles), K=128.
    f32x4 acc1[2][4];
    #pragma unroll
    for (int mt = 0; mt < 2; ++mt)
        #pragma unroll
        for (int i = 0; i < 4; ++i)
            acc1[mt][i] = (f32x4){0.f, 0.f, 0.f, 0.f};
    #pragma unroll
    for (int kk = 0; kk < 4; ++kk) {
        int k0 = kk * 32 + lk8;
        float a0f[8], a1f[8];
        *(float4*)&a0f[0] = *(const float4*)&s_y[lrow][k0];
        *(float4*)&a0f[4] = *(const float4*)&s_y[lrow][k0 + 4];
        *(float4*)&a1f[0] = *(const float4*)&s_y[16 + lrow][k0];
        *(float4*)&a1f[4] = *(const float4*)&s_y[16 + lrow][k0 + 4];
        bf16x8 a0h, a0l, a1h, a1l;
        split8(a0f, a0h, a0l);
        split8(a1f, a1h, a1l);
        #pragma unroll
        for (int i = 0; i < 4; ++i) {
            int col = (wv << 6) + (i << 4) + lrow;
            bf16x8 bh = *(const bf16x8*)(w1h + col * 128 + k0);
            bf16x8 bl = *(const bf16x8*)(w1l + col * 128 + k0);
            acc1[0][i] = __builtin_amdgcn_mfma_f32_16x16x32_bf16(a0l, bh, acc1[0][i], 0, 0, 0);
            acc1[0][i] = __builtin_amdgcn_mfma_f32_16x16x32_bf16(a0h, bl, acc1[0][i], 0, 0, 0);
            acc1[0][i] = __builtin_amdgcn_mfma_f32_16x16x32_bf16(a0h, bh, acc1[0][i], 0, 0, 0);
            acc1[1][i] = __builtin_amdgcn_mfma_f32_16x16x32_bf16(a1l, bh, acc1[1][i], 0, 0, 0);
            acc1[1][i] = __builtin_amdgcn_mfma_f32_16x16x32_bf16(a1h, bl, acc1[1][i], 0, 0, 0);
            acc1[1][i] = __builtin_amdgcn_mfma_f32_16x16x32_bf16(a1h, bh, acc1[1][i], 0, 0, 0);
        }
    }
    // epilogue: +b1, relu -> s_t (fp32; lanes 0-15 write consecutive cols)
    #pragma unroll
    for (int mt = 0; mt < 2; ++mt) {
        #pragma unroll
        for (int i = 0; i < 4; ++i) {
            int col = (wv << 6) + (i << 4) + lrow;
            float bv = b_ffn1[col];
            #pragma unroll
            for (int r = 0; r < 4; ++r) {
                int row = (mt << 4) + ((ln >> 4) << 2) + r;
                s_t[row][col] = fmaxf(acc1[mt][i][r] + bv, 0.f);
            }
        }
    }
    __syncthreads();

    // FFN2: ffn = t @ W2 + b2. M=32 (2 tiles), per-wave N=32 (2 tiles), K=256.
    f32x4 acc2[2][2];
    #pragma unroll
    for (int mt = 0; mt < 2; ++mt)
        #pragma unroll
        for (int c = 0; c < 2; ++c)
            acc2[mt][c] = (f32x4){0.f, 0.f, 0.f, 0.f};
    #pragma unroll
    for (int kk = 0; kk < 8; ++kk) {
        int k0 = kk * 32 + lk8;
        float a0f[8], a1f[8];
        *(float4*)&a0f[0] = *(const float4*)&s_t[lrow][k0];
        *(float4*)&a0f[4] = *(const float4*)&s_t[lrow][k0 + 4];
        *(float4*)&a1f[0] = *(const float4*)&s_t[16 + lrow][k0];
        *(float4*)&a1f[4] = *(const float4*)&s_t[16 + lrow][k0 + 4];
        bf16x8 a0h, a0l, a1h, a1l;
        split8(a0f, a0h, a0l);
        split8(a1f, a1h, a1l);
        #pragma unroll
        for (int c = 0; c < 2; ++c) {
            int col = (wv << 5) + (c << 4) + lrow;
            bf16x8 bh = *(const bf16x8*)(w2h + col * 256 + k0);
            bf16x8 bl = *(const bf16x8*)(w2l + col * 256 + k0);
            acc2[0][c] = __builtin_amdgcn_mfma_f32_16x16x32_bf16(a0l, bh, acc2[0][c], 0, 0, 0);
            acc2[0][c] = __builtin_amdgcn_mfma_f32_16x16x32_bf16(a0h, bl, acc2[0][c], 0, 0, 0);
            acc2[0][c] = __builtin_amdgcn_mfma_f32_16x16x32_bf16(a0h, bh, acc2[0][c], 0, 0, 0);
            acc2[1][c] = __builtin_amdgcn_mfma_f32_16x16x32_bf16(a1l, bh, acc2[1][c], 0, 0, 0);
            acc2[1][c] = __builtin_amdgcn_mfma_f32_16x16x32_bf16(a1h, bl, acc2[1][c], 0, 0, 0);
            acc2[1][c] = __builtin_amdgcn_mfma_f32_16x16x32_bf16(a1h, bh, acc2[1][c], 0, 0, 0);
        }
    }
    // epilogue: y += ffn + b2  (disjoint (row,col) per lane across block)
    #pragma unroll
    for (int mt = 0; mt < 2; ++mt) {
        #pragma unroll
        for (int c = 0; c < 2; ++c) {
            int col = (wv << 5) + (c << 4) + lrow;
            float bv = b_ffn2[col];
            #pragma unroll
            for (int r = 0; r < 4; ++r) {
                int row = (mt << 4) + ((ln >> 4) << 2) + r;
                s_y[row][col] += acc2[mt][c][r] + bv;
            }
        }
    }
    __syncthreads();
    // LayerNorm stats: 8 threads per node
    {
        int n = tid >> 3, kb = (tid & 7) * 16;
        float s = 0.f, ss = 0.f;
        #pragma unroll
        for (int k = 0; k < 16; k += 4) {
            float4 v = *(const float4*)&s_y[n][kb + k];
            s  += v.x + v.y + v.z + v.w;
            ss += v.x * v.x + v.y * v.y + v.z * v.z + v.w * v.w;
        }
        s  += __shfl_xor(s, 1, 64);  ss += __shfl_xor(ss, 1, 64);
        s  += __shfl_xor(s, 2, 64);  ss += __shfl_xor(ss, 2, 64);
        s  += __shfl_xor(s, 4, 64);  ss += __shfl_xor(ss, 4, 64);
        if ((tid & 7) == 0) {
            float mu = s * (1.f / 128.f);
            float var = ss * (1.f / 128.f) - mu * mu;
            s_mu[n] = mu;
            s_rs[n] = rsqrtf(fmaxf(var, 0.f) + 1e-5f);
        }
    }
    __syncthreads();
    // normalize + store (fp32)
    for (int it = 0; it < 4; ++it) {
        int idx4 = (it * 256 + tid) * 4;
        int n = idx4 >> 7, j = idx4 & 127;
        if (n < nn) {
            float mu = s_mu[n], rs = s_rs[n];
            float4 gv = *(const float4*)(gamma + j);
            float4 bv = *(const float4*)(beta + j);
            float4 v = *(const float4*)&s_y[n][j];
            float4 o;
            o.x = (v.x - mu) * rs * gv.x + bv.x;
            o.y = (v.y - mu) * rs * gv.y + bv.y;
            o.z = (v.z - mu) * rs * gv.z + bv.z;
            o.w = (v.w - mu) * rs * gv.w + bv.w;
            *(float4*)(out + (n0 + n) * 128 + j) = o;
        }
    }
}

// ---------------------------------------------------------------------------
extern "C" void kernel_launch(void* const* d_in, const int* in_sizes, int n_in,
                              void* d_out, int out_size, void* d_ws, size_t ws_size,
                              hipStream_t stream) {
    const float* x         = (const float*)d_in[0];
    const float* edge_attr = (const float*)d_in[1];
    const int* edge_index  = (const int*)d_in[17];
    float* out = (float*)d_out;

    char* base = (char*)d_ws;
    // workspace layout (29,600,064 B total, hardware-proven extents):
    float* sum_ea  = (float*)(base + 16);                     // 16 B
    // region A (old count region, 200000 B @ +32):
    int*   rhist   = (int*)  (base + 32);                     // 256*64*4 = 65536
    bf16*  w1t_hi  = (bf16*) (base + 32 + 65536);             // 65536 (written after rhist dead)
    bf16*  w1t_lo  = (bf16*) (base + 32 + 131072);            // 65536 -> ends 196640 < 200032
    int*   off     = (int*)  (base + 200032);                 // 200004 (+pad)
    // region C (old cursor region, 200000 B @ +400064):
    int*   base_r  = (int*)  (base + 400064);                 // 50 ints (pad to 256)
    bf16*  w2t_hi  = (bf16*) (base + 400064 + 256);           // 65536 (written after base_r dead)
    bf16*  w2t_lo  = (bf16*) (base + 400064 + 256 + 65536);   // ends 531392 < 600064
    unsigned int* perm = (unsigned int*)(base + 600064);      // 3400000
    bf16*  xl      = (bf16*) (base + 4000064);                // 12800000
    bf16*  xr      = (bf16*) (base + 16800064);               // 12800000
    // xform weight split pairs: perm head +1024 (consumed by k_fuse, dead
    // before k_group writes perm). 4 x 32768 B.
    bf16*  wxlh    = (bf16*) (base + 600064 + 1024);
    bf16*  wxll    = (bf16*) (base + 600064 + 1024 + 32768);
    bf16*  wxrh    = (bf16*) (base + 600064 + 1024 + 65536);
    bf16*  wxrl    = (bf16*) (base + 600064 + 1024 + 98304);
    // range-partitioned (dst,payload) pairs: head of d_out (dead until k_agg).
    uint2* tmp2    = (uint2*)d_out;                           // 850176*8 = 6.8 MB

    hipMemsetAsync(sum_ea, 0, 16, stream);

    const int NTILES = (NODES + 31) / 32;  // 1563

    k_wxf     <<<128, 256, 0, stream>>>((const float*)d_in[2], (const float*)d_in[4],
                                        wxlh, wxll, wxrh, wxrl);
    k_fuse    <<<FUSE_GRID, 256, 0, stream>>>(edge_attr, edge_index, sum_ea, rhist,
                                              x, wxlh, wxll, wxrh, wxrl,
                                              (const float*)d_in[3], (const float*)d_in[5],
                                              xl, xr);
    k_rscan   <<<1, 256, 0, stream>>>(rhist, base_r, off);
    k_scatter <<<SB, 256, 0, stream>>>(edge_index, edge_attr, sum_ea, rhist, tmp2);
    k_group   <<<NRANGE, 1024, 0, stream>>>(tmp2, base_r, off, perm);
    k_wconv   <<<256, 256, 0, stream>>>((const float*)d_in[11], (const float*)d_in[13],
                                        w1t_hi, w1t_lo, w2t_hi, w2t_lo);
    k_agg     <<<3125, 256, 0, stream>>>((const unsigned int*)xl,
                                         (const unsigned int*)xr,
                                         perm, off,
                                         (const float*)d_in[6], (const float*)d_in[7],
                                         out);
    k_epi     <<<NTILES, 256, 0, stream>>>(out, x, (const float*)d_in[8],
                                           (const float*)d_in[9], (const float*)d_in[10],
                                           w1t_hi, w1t_lo, (const float*)d_in[12],
                                           w2t_hi, w2t_lo, (const float*)d_in[14],
                                           (const float*)d_in[15], (const float*)d_in[16],
                                           out);
}